// Round 1
// baseline (1186.259 us; speedup 1.0000x reference)
//
#include <hip/hip_runtime.h>
#include <math.h>

typedef _Float16 h8 __attribute__((ext_vector_type(8)));
typedef float f4 __attribute__((ext_vector_type(4)));

#define BATCH 32768

// ---------------- prep: input slices -> fp16, padded, bias-const col ----------------
__global__ __launch_bounds__(256) void prep_input_k(const float* __restrict__ in,
    _Float16* __restrict__ pose, _Float16* __restrict__ goal, _Float16* __restrict__ gate)
{
  const int b = blockIdx.x;
  const float* r = in + (size_t)b * 556;
  for (int c = threadIdx.x; c < 448; c += 256) {
    float v = (c < 400) ? r[c] : (c == 400 ? 1.0f : 0.0f);
    pose[(size_t)b * 448 + c] = (_Float16)v;
  }
  if (threadIdx.x < 128) {
    int c = threadIdx.x;
    float v = (c < 78) ? r[400 + c] : (c == 78 ? 1.0f : 0.0f);
    goal[(size_t)b * 128 + c] = (_Float16)v;
    float v2 = (c < 78) ? r[478 + c] : (c == 78 ? 1.0f : 0.0f);
    gate[(size_t)b * 128 + c] = (_Float16)v2;
  }
}

// ---------------- prep: weight transpose+convert  out[n][c] ----------------
// c < K        : W[c*Nld + n]   (W is [K][N] flat; for experts K = E*K_e)
// c-K < biasCols: bias[(c-K)*biasLd + n]   (biasLd=0 => vector bias)
// else 0. n >= N => 0.
__global__ __launch_bounds__(256) void prep_w_k(const float* __restrict__ W,
    const float* __restrict__ bias, _Float16* __restrict__ out,
    int K, int N, int Nld, int Kout, int biasCols, int biasLd)
{
  int c = blockIdx.x * 256 + threadIdx.x;
  if (c >= Kout) return;
  int n = blockIdx.y;
  float v = 0.0f;
  if (c < K) { if (n < N) v = W[(size_t)c * Nld + n]; }
  else if (c - K < biasCols) { if (n < N) v = bias[(size_t)(c - K) * biasLd + n]; }
  out[(size_t)n * Kout + c] = (_Float16)v;
}

// ---------------- main GEMM ----------------
// C = A(fp16)[M][ldA] @ Bw(fp16, N-major [n][k])[.][ldB],  tile 128x128, BK=64
// EXPERT: virtual A_big[b, c*64+j]: for c < nChunks-1: e=c/nKCe, A[b][ (c-e*nKCe)*64+j ] * wpad[b][e]
//         last chunk: wpad[b][j] (bias-blend chunk, unscaled)
template<bool EXPERT, bool EPI_BIAS, bool DO_ELU, bool OUT_F32>
__global__ __launch_bounds__(256, 2) void gemm_k(
    const _Float16* __restrict__ A, const _Float16* __restrict__ Bw,
    void* __restrict__ OutP, const float* __restrict__ bias,
    const _Float16* __restrict__ wpad,
    int ldA, int ldB, int ldO, int nChunks, int nKCe, int nLimit)
{
  __shared__ __align__(16) _Float16 As[128 * 64];
  __shared__ __align__(16) _Float16 Bs[128 * 64];

  const int t = threadIdx.x;
  const int m0 = blockIdx.x * 128;
  const int n0 = blockIdx.y * 128;
  const int wid = t >> 6;
  const int lane = t & 63;
  const int wm = (wid >> 1) * 64;
  const int wn = (wid & 1) * 64;
  const int lr = lane & 15;
  const int lg = lane >> 4;

  // staging geometry: slot = t + 256*i2 ; row = t/8 + 32*i2 ; s = t&7 (const)
  const int srow = t >> 3;
  const int ss = t & 7;
  const int sxor8 = (ss ^ (srow & 7)) << 3;  // swizzled half-offset within row

  f4 acc[4][4];
  #pragma unroll
  for (int i = 0; i < 4; ++i)
    #pragma unroll
    for (int j = 0; j < 4; ++j) { f4 z = {0.f, 0.f, 0.f, 0.f}; acc[i][j] = z; }

  h8 av[4], bv[4];

  auto load_chunk = [&](int c) {
    const _Float16* bp = Bw + (size_t)(n0 + srow) * ldB + c * 64 + ss * 8;
    #pragma unroll
    for (int i2 = 0; i2 < 4; ++i2)
      bv[i2] = *reinterpret_cast<const h8*>(bp + (size_t)32 * i2 * ldB);
    if (EXPERT) {
      if (c == nChunks - 1) {
        const _Float16* ap = wpad + (size_t)(m0 + srow) * 64 + ss * 8;
        #pragma unroll
        for (int i2 = 0; i2 < 4; ++i2)
          av[i2] = *reinterpret_cast<const h8*>(ap + (size_t)32 * i2 * 64);
      } else {
        int e = c / nKCe;
        int kb = (c - e * nKCe) * 64 + ss * 8;
        const _Float16* ap = A + (size_t)(m0 + srow) * ldA + kb;
        const _Float16* wp = wpad + (size_t)(m0 + srow) * 64 + e;
        #pragma unroll
        for (int i2 = 0; i2 < 4; ++i2) {
          h8 v = *reinterpret_cast<const h8*>(ap + (size_t)32 * i2 * ldA);
          _Float16 wv = wp[(size_t)32 * i2 * 64];
          #pragma unroll
          for (int q = 0; q < 8; ++q) v[q] = v[q] * wv;
          av[i2] = v;
        }
      }
    } else {
      const _Float16* ap = A + (size_t)(m0 + srow) * ldA + c * 64 + ss * 8;
      #pragma unroll
      for (int i2 = 0; i2 < 4; ++i2)
        av[i2] = *reinterpret_cast<const h8*>(ap + (size_t)32 * i2 * ldA);
    }
  };

  load_chunk(0);

  for (int c = 0; c < nChunks; ++c) {
    {
      int base = srow * 64 + sxor8;
      #pragma unroll
      for (int i2 = 0; i2 < 4; ++i2) {
        *reinterpret_cast<h8*>(&As[base + i2 * 2048]) = av[i2];
        *reinterpret_cast<h8*>(&Bs[base + i2 * 2048]) = bv[i2];
      }
    }
    __syncthreads();
    if (c + 1 < nChunks) load_chunk(c + 1);  // overlap next-chunk HBM/L2 latency with MFMA
    #pragma unroll
    for (int kk = 0; kk < 2; ++kk) {
      h8 af[4], bf[4];
      const int kslot = kk * 4 + lg;
      #pragma unroll
      for (int i = 0; i < 4; ++i) {
        int row = wm + i * 16 + lr;
        af[i] = *reinterpret_cast<const h8*>(&As[row * 64 + ((kslot ^ (row & 7)) << 3)]);
      }
      #pragma unroll
      for (int j = 0; j < 4; ++j) {
        int row = wn + j * 16 + lr;
        bf[j] = *reinterpret_cast<const h8*>(&Bs[row * 64 + ((kslot ^ (row & 7)) << 3)]);
      }
      #pragma unroll
      for (int i = 0; i < 4; ++i)
        #pragma unroll
        for (int j = 0; j < 4; ++j)
          acc[i][j] = __builtin_amdgcn_mfma_f32_16x16x32_f16(af[i], bf[j], acc[i][j], 0, 0, 0);
    }
    __syncthreads();
  }

  // epilogue: C frag (i,j): col = n0+wn+j*16+(lane&15), rows = m0+wm+i*16+(lane>>4)*4+r
  #pragma unroll
  for (int j = 0; j < 4; ++j) {
    const int col = n0 + wn + j * 16 + lr;
    if (col >= nLimit) continue;
    float bvv = 0.0f;
    if (EPI_BIAS) bvv = bias[col];
    #pragma unroll
    for (int i = 0; i < 4; ++i) {
      const int rowb = m0 + wm + i * 16 + lg * 4;
      #pragma unroll
      for (int r = 0; r < 4; ++r) {
        float x = acc[i][j][r] + bvv;
        if (DO_ELU) x = (x > 0.0f) ? x : expm1f(x);
        if (OUT_F32)
          reinterpret_cast<float*>(OutP)[(size_t)(rowb + r) * ldO + col] = x;
        else
          reinterpret_cast<_Float16*>(OutP)[(size_t)(rowb + r) * ldO + col] = (_Float16)x;
      }
    }
  }
}

// ---------------- gating final layer (N=10) + softmax -> wpad[B][64] ----------------
__global__ __launch_bounds__(256) void gate_softmax_k(const _Float16* __restrict__ gb,
    const float* __restrict__ W2, const float* __restrict__ b2, _Float16* __restrict__ wpad)
{
  __shared__ float W2s[5120];
  for (int i = threadIdx.x; i < 5120; i += 256) W2s[i] = W2[i];
  __syncthreads();
  const int b = blockIdx.x * 256 + threadIdx.x;
  float acc[10];
  #pragma unroll
  for (int o = 0; o < 10; ++o) acc[o] = b2[o];
  const _Float16* row = gb + (size_t)b * 512;
  for (int k0 = 0; k0 < 512; k0 += 8) {
    h8 x = *reinterpret_cast<const h8*>(row + k0);
    #pragma unroll
    for (int jj = 0; jj < 8; ++jj) {
      float xv = (float)x[jj];
      #pragma unroll
      for (int o = 0; o < 10; ++o) acc[o] += xv * W2s[(k0 + jj) * 10 + o];
    }
  }
  float mx = acc[0];
  #pragma unroll
  for (int o = 1; o < 10; ++o) mx = fmaxf(mx, acc[o]);
  float s = 0.0f;
  #pragma unroll
  for (int o = 0; o < 10; ++o) { acc[o] = expf(acc[o] - mx); s += acc[o]; }
  float inv = 1.0f / s;
  _Float16* wr = wpad + (size_t)b * 64;
  #pragma unroll
  for (int o = 0; o < 10; ++o) wr[o] = (_Float16)(acc[o] * inv);
  #pragma unroll
  for (int o = 10; o < 64; ++o) wr[o] = (_Float16)0.0f;
}

extern "C" void kernel_launch(void* const* d_in, const int* in_sizes, int n_in,
                              void* d_out, int out_size, void* d_ws, size_t ws_size,
                              hipStream_t stream)
{
  const float* input_ = (const float*)d_in[0];
  const float* e0_W0 = (const float*)d_in[1];
  const float* e0_b0 = (const float*)d_in[2];
  const float* e0_W1 = (const float*)d_in[3];
  const float* e0_b1 = (const float*)d_in[4];
  const float* e1_W0 = (const float*)d_in[5];
  const float* e1_b0 = (const float*)d_in[6];
  const float* e1_W1 = (const float*)d_in[7];
  const float* e1_b1 = (const float*)d_in[8];
  const float* g_W0  = (const float*)d_in[9];
  const float* g_b0  = (const float*)d_in[10];
  const float* g_W1  = (const float*)d_in[11];
  const float* g_b1  = (const float*)d_in[12];
  const float* g_W2  = (const float*)d_in[13];
  const float* g_b2  = (const float*)d_in[14];
  const float* m_W0  = (const float*)d_in[15];
  const float* m_b0  = (const float*)d_in[16];
  const float* m_W1  = (const float*)d_in[17];
  const float* m_b1  = (const float*)d_in[18];
  const float* m_W2  = (const float*)d_in[19];
  const float* m_b2  = (const float*)d_in[20];
  (void)in_sizes; (void)n_in; (void)out_size; (void)ws_size;

  char* ws = (char*)d_ws;
  size_t off = 0;
  auto alloc = [&](size_t bytes) { char* p = ws + off; off += (bytes + 255) & ~(size_t)255; return p; };

  const size_t Bn = BATCH;
  // aliased activation regions (lifetimes are disjoint, stream-ordered):
  _Float16* wsA    = (_Float16*)alloc(Bn * 512 * 2);  // pose16[448] -> ga16 -> x1
  _Float16* wsB    = (_Float16*)alloc(Bn * 512 * 2);  // h0a -> gb
  _Float16* wsC    = (_Float16*)alloc(Bn * 640 * 2);  // feat -> x2
  _Float16* goal16 = (_Float16*)alloc(Bn * 128 * 2);
  _Float16* gate16 = (_Float16*)alloc(Bn * 128 * 2);
  _Float16* h1a16  = (_Float16*)alloc(Bn * 128 * 2);
  _Float16* wpad16 = (_Float16*)alloc(Bn * 64 * 2);
  _Float16* e0W0t  = (_Float16*)alloc((size_t)512 * 448 * 2);
  _Float16* e0W1t  = (_Float16*)alloc((size_t)512 * 512 * 2);
  _Float16* e1W0t  = (_Float16*)alloc((size_t)128 * 128 * 2);
  _Float16* e1W1t  = (_Float16*)alloc((size_t)128 * 128 * 2);
  _Float16* gW0t   = (_Float16*)alloc((size_t)512 * 128 * 2);
  _Float16* gW1t   = (_Float16*)alloc((size_t)512 * 512 * 2);
  _Float16* W0b    = (_Float16*)alloc((size_t)512 * 6464 * 2);
  _Float16* W1b    = (_Float16*)alloc((size_t)512 * 5184 * 2);
  _Float16* W2b    = (_Float16*)alloc((size_t)640 * 5184 * 2);

  dim3 blk(256);
  const int BIG = 1 << 30;

  prep_input_k<<<BATCH, blk, 0, stream>>>(input_, wsA, goal16, gate16);

  prep_w_k<<<dim3(2, 512),  blk, 0, stream>>>(e0_W0, e0_b0, e0W0t, 400, 512, 512, 448, 1, 0);
  prep_w_k<<<dim3(2, 512),  blk, 0, stream>>>(e0_W1, nullptr, e0W1t, 512, 512, 512, 512, 0, 0);
  prep_w_k<<<dim3(1, 128),  blk, 0, stream>>>(e1_W0, e1_b0, e1W0t, 78, 128, 128, 128, 1, 0);
  prep_w_k<<<dim3(1, 128),  blk, 0, stream>>>(e1_W1, nullptr, e1W1t, 128, 128, 128, 128, 0, 0);
  prep_w_k<<<dim3(1, 512),  blk, 0, stream>>>(g_W0, g_b0, gW0t, 78, 512, 512, 128, 1, 0);
  prep_w_k<<<dim3(2, 512),  blk, 0, stream>>>(g_W1, nullptr, gW1t, 512, 512, 512, 512, 0, 0);
  prep_w_k<<<dim3(26, 512), blk, 0, stream>>>(m_W0, m_b0, W0b, 6400, 512, 512, 6464, 10, 512);
  prep_w_k<<<dim3(21, 512), blk, 0, stream>>>(m_W1, m_b1, W1b, 5120, 512, 512, 5184, 10, 512);
  prep_w_k<<<dim3(21, 640), blk, 0, stream>>>(m_W2, m_b2, W2b, 5120, 578, 578, 5184, 10, 578);

  // encoder 0: pose(448) -> h0a(512) -> feat[:,0:512]
  gemm_k<false, false, true, false><<<dim3(256, 4), blk, 0, stream>>>(
      wsA, e0W0t, wsB, nullptr, nullptr, 448, 448, 512, 7, 0, BIG);
  gemm_k<false, true, true, false><<<dim3(256, 4), blk, 0, stream>>>(
      wsB, e0W1t, wsC, e0_b1, nullptr, 512, 512, 640, 8, 0, BIG);
  // encoder 1: goal(128) -> h1a(128) -> feat[:,512:640]
  gemm_k<false, false, true, false><<<dim3(256, 1), blk, 0, stream>>>(
      goal16, e1W0t, h1a16, nullptr, nullptr, 128, 128, 128, 2, 0, BIG);
  gemm_k<false, true, true, false><<<dim3(256, 1), blk, 0, stream>>>(
      h1a16, e1W1t, wsC + 512, e1_b1, nullptr, 128, 128, 640, 2, 0, BIG);
  // gating: gate(128) -> ga(512) -> gb(512) -> softmax w
  gemm_k<false, false, true, false><<<dim3(256, 4), blk, 0, stream>>>(
      gate16, gW0t, wsA, nullptr, nullptr, 128, 128, 512, 2, 0, BIG);
  gemm_k<false, true, true, false><<<dim3(256, 4), blk, 0, stream>>>(
      wsA, gW1t, wsB, g_b1, nullptr, 512, 512, 512, 8, 0, BIG);
  gate_softmax_k<<<dim3(BATCH / 256), blk, 0, stream>>>(wsB, g_W2, g_b2, wpad16);
  // experts: feat(640) -> x1(512) -> x2(512) -> pred(578)
  gemm_k<true, false, true, false><<<dim3(256, 4), blk, 0, stream>>>(
      wsC, W0b, wsA, nullptr, wpad16, 640, 6464, 512, 101, 10, BIG);
  gemm_k<true, false, true, false><<<dim3(256, 4), blk, 0, stream>>>(
      wsA, W1b, wsC, nullptr, wpad16, 512, 5184, 512, 81, 8, BIG);
  gemm_k<true, false, false, true><<<dim3(256, 5), blk, 0, stream>>>(
      wsC, W2b, d_out, nullptr, wpad16, 512, 5184, 578, 81, 8, 578);
}

// Round 3
// 1154.561 us; speedup vs baseline: 1.0275x; 1.0275x over previous
//
#include <hip/hip_runtime.h>
#include <math.h>

typedef _Float16 h8 __attribute__((ext_vector_type(8)));
typedef float f4 __attribute__((ext_vector_type(4)));

#define BATCH 32768

__device__ __forceinline__ void gload16(const void* g, void* l) {
  __builtin_amdgcn_global_load_lds(
      (const __attribute__((address_space(1))) unsigned int*)g,
      (__attribute__((address_space(3))) unsigned int*)l, 16, 0, 0);
}

// ---------------- prep: input slices -> fp16, padded, bias-const col ----------------
__global__ __launch_bounds__(256) void prep_input_k(const float* __restrict__ in,
    _Float16* __restrict__ pose, _Float16* __restrict__ goal, _Float16* __restrict__ gate)
{
  const int b = blockIdx.x;
  const float* r = in + (size_t)b * 556;
  for (int c = threadIdx.x; c < 448; c += 256) {
    float v = (c < 400) ? r[c] : (c == 400 ? 1.0f : 0.0f);
    pose[(size_t)b * 448 + c] = (_Float16)v;
  }
  if (threadIdx.x < 128) {
    int c = threadIdx.x;
    float v = (c < 78) ? r[400 + c] : (c == 78 ? 1.0f : 0.0f);
    goal[(size_t)b * 128 + c] = (_Float16)v;
    float v2 = (c < 78) ? r[478 + c] : (c == 78 ? 1.0f : 0.0f);
    gate[(size_t)b * 128 + c] = (_Float16)v2;
  }
}

// ---------------- prep: coalesced LDS-tiled transpose  out[n][c] <- W[c][n] ----------------
// c < K: W[c*Nld+n]; c-K < biasCols: bias[(c-K)*biasLd + n]; else 0. n>=N => 0.
__global__ __launch_bounds__(256) void prep_wt_k(const float* __restrict__ W,
    const float* __restrict__ bias, _Float16* __restrict__ out,
    int K, int N, int Nld, int Kout, int biasCols, int biasLd)
{
  __shared__ float tile[64 * 65];
  const int t = threadIdx.x;
  const int c0 = blockIdx.x * 64;
  const int n0 = blockIdx.y * 64;
  {
    const int nn = t & 63;
    #pragma unroll
    for (int i = 0; i < 16; ++i) {
      int cc = (t >> 6) + i * 4;
      int c = c0 + cc, n = n0 + nn;
      float v = 0.0f;
      if (n < N) {
        if (c < K) v = W[(size_t)c * Nld + n];
        else if (c - K < biasCols) v = bias[(size_t)(c - K) * biasLd + n];
      }
      tile[cc * 65 + nn] = v;
    }
  }
  __syncthreads();
  {
    const int cc = t & 63;
    #pragma unroll
    for (int i = 0; i < 16; ++i) {
      int nn = (t >> 6) + i * 4;
      out[(size_t)(n0 + nn) * Kout + c0 + cc] = (_Float16)tile[cc * 65 + nn];
    }
  }
}

// ---------------- simple GEMM: 128x128 tile, BK=64, dbuf LDS, gload_lds both ----------------
template<bool EPI_BIAS, bool DO_ELU, bool OUT_F32>
__global__ __launch_bounds__(256, 2) void gemm_k(
    const _Float16* __restrict__ A, const _Float16* __restrict__ Bw,
    void* __restrict__ OutP, const float* __restrict__ bias,
    int ldA, int ldB, int ldO, int nChunks, int nLimit)
{
  __shared__ __align__(16) _Float16 As[2][128 * 64];
  __shared__ __align__(16) _Float16 Bs[2][128 * 64];

  const int t = threadIdx.x;
  const int m0 = blockIdx.x * 128;
  const int n0 = blockIdx.y * 128;
  const int wid = t >> 6;
  const int lane = t & 63;
  const int wm = (wid >> 1) * 64;
  const int wn = (wid & 1) * 64;
  const int lr = lane & 15;
  const int lg = lane >> 4;

  // gload geometry: per issue, lane l -> row +(l>>3), slot l&7; source col pre-swizzled
  const int gr = lane >> 3;
  const int gcol = ((lane & 7) ^ gr) * 8;
  const _Float16* Abase = A + (size_t)(m0 + wid * 32 + gr) * ldA + gcol;
  const _Float16* Bbase = Bw + (size_t)(n0 + wid * 32 + gr) * ldB + gcol;

  f4 acc[4][4];
  #pragma unroll
  for (int i = 0; i < 4; ++i)
    #pragma unroll
    for (int j = 0; j < 4; ++j) { f4 z = {0.f, 0.f, 0.f, 0.f}; acc[i][j] = z; }

  auto issue = [&](int c, int buf) {
    #pragma unroll
    for (int i = 0; i < 4; ++i) {
      gload16(Abase + (size_t)(i * 8) * ldA + c * 64, &As[buf][(wid * 32 + i * 8) * 64]);
      gload16(Bbase + (size_t)(i * 8) * ldB + c * 64, &Bs[buf][(wid * 32 + i * 8) * 64]);
    }
  };

  auto mfma_step = [&](const _Float16* as, const _Float16* bs) {
    #pragma unroll
    for (int kk = 0; kk < 2; ++kk) {
      h8 af[4], bf[4];
      const int kslot = kk * 4 + lg;
      #pragma unroll
      for (int i = 0; i < 4; ++i) {
        const int row = wm + i * 16 + lr;
        af[i] = *reinterpret_cast<const h8*>(&as[row * 64 + ((kslot ^ (row & 7)) << 3)]);
      }
      #pragma unroll
      for (int j = 0; j < 4; ++j) {
        const int row = wn + j * 16 + lr;
        bf[j] = *reinterpret_cast<const h8*>(&bs[row * 64 + ((kslot ^ (row & 7)) << 3)]);
      }
      #pragma unroll
      for (int i = 0; i < 4; ++i)
        #pragma unroll
        for (int j = 0; j < 4; ++j)
          acc[i][j] = __builtin_amdgcn_mfma_f32_16x16x32_f16(af[i], bf[j], acc[i][j], 0, 0, 0);
    }
  };

  issue(0, 0);
  int cur = 0;
  for (int c = 0; c < nChunks; ++c) {
    __syncthreads();                       // vmcnt(0): buf[cur] ready; all done reading buf[cur^1]
    if (c + 1 < nChunks) issue(c + 1, cur ^ 1);
    mfma_step(As[cur], Bs[cur]);
    cur ^= 1;
  }

  #pragma unroll
  for (int j = 0; j < 4; ++j) {
    const int col = n0 + wn + j * 16 + lr;
    if (col >= nLimit) continue;
    float bvv = 0.0f;
    if (EPI_BIAS) bvv = bias[col];
    #pragma unroll
    for (int i = 0; i < 4; ++i) {
      const int rowb = m0 + wm + i * 16 + lg * 4;
      #pragma unroll
      for (int r = 0; r < 4; ++r) {
        float x = acc[i][j][r] + bvv;
        if (DO_ELU) x = (x > 0.0f) ? x : expm1f(x);
        if (OUT_F32)
          reinterpret_cast<float*>(OutP)[(size_t)(rowb + r) * ldO + col] = x;
        else
          reinterpret_cast<_Float16*>(OutP)[(size_t)(rowb + r) * ldO + col] = (_Float16)x;
      }
    }
  }
}

// ---------------- expert GEMM: virtual K = E*KC chunks (+1 bias chunk) ----------------
// A raw-prefetched to regs, scaled by w[e] (static e) at ds_write; B via gload_lds dbuf.
template<int KC, bool DO_ELU, bool OUT_F32>
__global__ __launch_bounds__(256, 2) void expert_k(
    const _Float16* __restrict__ A, const _Float16* __restrict__ Bw,
    void* __restrict__ OutP, const _Float16* __restrict__ wpad,
    int ldA, int ldB, int ldO, int nLimit)
{
  constexpr int E = 10;
  __shared__ __align__(16) _Float16 As[2][128 * 64];
  __shared__ __align__(16) _Float16 Bs[2][128 * 64];

  const int t = threadIdx.x;
  const int m0 = blockIdx.x * 128;
  const int n0 = blockIdx.y * 128;
  const int wid = t >> 6;
  const int lane = t & 63;
  const int wm = (wid >> 1) * 64;
  const int wn = (wid & 1) * 64;
  const int lr = lane & 15;
  const int lg = lane >> 4;

  // A reg-staging geometry (swizzle applied at ds_write)
  const int srow = t >> 3;
  const int ss = t & 7;
  const int wbase = srow * 64 + ((ss ^ (srow & 7)) << 3);

  // B gload geometry (swizzle applied at global source)
  const int gr = lane >> 3;
  const int gcol = ((lane & 7) ^ gr) * 8;
  const _Float16* Bbase = Bw + (size_t)(n0 + wid * 32 + gr) * ldB + gcol;

  const _Float16* Arow = A + (size_t)(m0 + srow) * ldA + ss * 8;
  const _Float16* Wrow = wpad + (size_t)(m0 + srow) * 64;

  // gate weights for this thread's 4 staging rows, held in regs (static-indexed)
  h8 wlo[4], whi[4];
  #pragma unroll
  for (int i2 = 0; i2 < 4; ++i2) {
    wlo[i2] = *reinterpret_cast<const h8*>(Wrow + (size_t)32 * i2 * 64);
    whi[i2] = *reinterpret_cast<const h8*>(Wrow + (size_t)32 * i2 * 64 + 8);
  }

  f4 acc[4][4];
  #pragma unroll
  for (int i = 0; i < 4; ++i)
    #pragma unroll
    for (int j = 0; j < 4; ++j) { f4 z = {0.f, 0.f, 0.f, 0.f}; acc[i][j] = z; }

  auto mfma_step = [&](const _Float16* as, const _Float16* bs) {
    #pragma unroll
    for (int kk = 0; kk < 2; ++kk) {
      h8 af[4], bf[4];
      const int kslot = kk * 4 + lg;
      #pragma unroll
      for (int i = 0; i < 4; ++i) {
        const int row = wm + i * 16 + lr;
        af[i] = *reinterpret_cast<const h8*>(&as[row * 64 + ((kslot ^ (row & 7)) << 3)]);
      }
      #pragma unroll
      for (int j = 0; j < 4; ++j) {
        const int row = wn + j * 16 + lr;
        bf[j] = *reinterpret_cast<const h8*>(&bs[row * 64 + ((kslot ^ (row & 7)) << 3)]);
      }
      #pragma unroll
      for (int i = 0; i < 4; ++i)
        #pragma unroll
        for (int j = 0; j < 4; ++j)
          acc[i][j] = __builtin_amdgcn_mfma_f32_16x16x32_f16(af[i], bf[j], acc[i][j], 0, 0, 0);
    }
  };

  // prologue: raw A chunk 0, B chunk 0
  h8 av[4];
  #pragma unroll
  for (int i2 = 0; i2 < 4; ++i2)
    av[i2] = *reinterpret_cast<const h8*>(Arow + (size_t)32 * i2 * ldA);
  #pragma unroll
  for (int i = 0; i < 4; ++i)
    gload16(Bbase + (size_t)(i * 8) * ldB, &Bs[0][(wid * 32 + i * 8) * 64]);

  int cur = 0;
  int bcol = 64;
  #pragma unroll
  for (int e = 0; e < E; ++e) {
    _Float16 wv[4];
    #pragma unroll
    for (int i2 = 0; i2 < 4; ++i2) wv[i2] = (e < 8) ? wlo[i2][e] : whi[i2][e - 8];
    #pragma unroll 1
    for (int kc = 0; kc < KC; ++kc) {
      // scaled ds_write of current chunk
      #pragma unroll
      for (int i2 = 0; i2 < 4; ++i2) {
        h8 v = av[i2];
        #pragma unroll
        for (int q = 0; q < 8; ++q) v[q] = v[q] * wv[i2];
        *reinterpret_cast<h8*>(&As[cur][wbase + i2 * 2048]) = v;
      }
      __syncthreads();
      // prefetch next A (raw) — BEFORE B issues so its vmcnt wait keeps B in flight
      {
        const bool lastc = (e == E - 1) && (kc == KC - 1);
        const _Float16* src;
        int sstride;
        if (lastc) { src = Wrow + ss * 8; sstride = 64; }            // bias chunk: wpad rows
        else {
          const int nk = (kc + 1 == KC) ? 0 : (kc + 1);
          src = Arow + nk * 64; sstride = ldA;
        }
        #pragma unroll
        for (int i2 = 0; i2 < 4; ++i2)
          av[i2] = *reinterpret_cast<const h8*>(src + (size_t)32 * i2 * sstride);
      }
      // issue next B chunk into the other buffer
      #pragma unroll
      for (int i = 0; i < 4; ++i)
        gload16(Bbase + (size_t)(i * 8) * ldB + bcol, &Bs[cur ^ 1][(wid * 32 + i * 8) * 64]);
      bcol += 64;
      mfma_step(As[cur], Bs[cur]);
      cur ^= 1;
    }
  }
  // bias-blend chunk (A = wpad rows, unscaled)
  #pragma unroll
  for (int i2 = 0; i2 < 4; ++i2)
    *reinterpret_cast<h8*>(&As[cur][wbase + i2 * 2048]) = av[i2];
  __syncthreads();
  mfma_step(As[cur], Bs[cur]);

  #pragma unroll
  for (int j = 0; j < 4; ++j) {
    const int col = n0 + wn + j * 16 + lr;
    if (col >= nLimit) continue;
    #pragma unroll
    for (int i = 0; i < 4; ++i) {
      const int rowb = m0 + wm + i * 16 + lg * 4;
      #pragma unroll
      for (int r = 0; r < 4; ++r) {
        float x = acc[i][j][r];
        if (DO_ELU) x = (x > 0.0f) ? x : expm1f(x);
        if (OUT_F32)
          reinterpret_cast<float*>(OutP)[(size_t)(rowb + r) * ldO + col] = x;
        else
          reinterpret_cast<_Float16*>(OutP)[(size_t)(rowb + r) * ldO + col] = (_Float16)x;
      }
    }
  }
}

// ---------------- gating final layer (N=10) + softmax -> wpad[B][64], 4 lanes/row ----------------
__global__ __launch_bounds__(256) void gate_softmax_k(const _Float16* __restrict__ gb,
    const float* __restrict__ W2, const float* __restrict__ b2, _Float16* __restrict__ wpad)
{
  __shared__ float W2s[5120];
  for (int i = threadIdx.x; i < 5120; i += 256) W2s[i] = W2[i];
  __syncthreads();
  const int t = threadIdx.x;
  const int sub = t & 3;
  const int b = blockIdx.x * 64 + (t >> 2);
  const _Float16* row = gb + (size_t)b * 512 + sub * 128;
  float acc[10];
  #pragma unroll
  for (int o = 0; o < 10; ++o) acc[o] = 0.0f;
  #pragma unroll 4
  for (int k0 = 0; k0 < 128; k0 += 8) {
    h8 x = *reinterpret_cast<const h8*>(row + k0);
    #pragma unroll
    for (int jj = 0; jj < 8; ++jj) {
      float xv = (float)x[jj];
      const int k = sub * 128 + k0 + jj;
      #pragma unroll
      for (int o = 0; o < 10; ++o) acc[o] += xv * W2s[k * 10 + o];
    }
  }
  #pragma unroll
  for (int o = 0; o < 10; ++o) {
    acc[o] += __shfl_xor(acc[o], 1);
    acc[o] += __shfl_xor(acc[o], 2);
    acc[o] += b2[o];
  }
  float mx = acc[0];
  #pragma unroll
  for (int o = 1; o < 10; ++o) mx = fmaxf(mx, acc[o]);
  float s = 0.0f;
  #pragma unroll
  for (int o = 0; o < 10; ++o) { acc[o] = expf(acc[o] - mx); s += acc[o]; }
  const float inv = 1.0f / s;
  h8 o0 = {0,0,0,0,0,0,0,0}, o1 = {0,0,0,0,0,0,0,0};
  if (sub == 0) {
    #pragma unroll
    for (int o = 0; o < 8; ++o) o0[o] = (_Float16)(acc[o] * inv);
    o1[0] = (_Float16)(acc[8] * inv);
    o1[1] = (_Float16)(acc[9] * inv);
  }
  _Float16* wr = wpad + (size_t)b * 64 + sub * 16;
  *reinterpret_cast<h8*>(wr) = o0;
  *reinterpret_cast<h8*>(wr + 8) = o1;
}

extern "C" void kernel_launch(void* const* d_in, const int* in_sizes, int n_in,
                              void* d_out, int out_size, void* d_ws, size_t ws_size,
                              hipStream_t stream)
{
  const float* input_ = (const float*)d_in[0];
  const float* e0_W0 = (const float*)d_in[1];
  const float* e0_b0 = (const float*)d_in[2];
  const float* e0_W1 = (const float*)d_in[3];
  const float* e0_b1 = (const float*)d_in[4];
  const float* e1_W0 = (const float*)d_in[5];
  const float* e1_b0 = (const float*)d_in[6];
  const float* e1_W1 = (const float*)d_in[7];
  const float* e1_b1 = (const float*)d_in[8];
  const float* g_W0  = (const float*)d_in[9];
  const float* g_b0  = (const float*)d_in[10];
  const float* g_W1  = (const float*)d_in[11];
  const float* g_b1  = (const float*)d_in[12];
  const float* g_W2  = (const float*)d_in[13];
  const float* g_b2  = (const float*)d_in[14];
  const float* m_W0  = (const float*)d_in[15];
  const float* m_b0  = (const float*)d_in[16];
  const float* m_W1  = (const float*)d_in[17];
  const float* m_b1  = (const float*)d_in[18];
  const float* m_W2  = (const float*)d_in[19];
  const float* m_b2  = (const float*)d_in[20];
  (void)in_sizes; (void)n_in; (void)out_size; (void)ws_size;

  char* ws = (char*)d_ws;
  size_t off = 0;
  auto alloc = [&](size_t bytes) { char* p = ws + off; off += (bytes + 255) & ~(size_t)255; return p; };

  const size_t Bn = BATCH;
  _Float16* wsA    = (_Float16*)alloc(Bn * 512 * 2);  // pose16[448] -> ga16 -> x1
  _Float16* wsB    = (_Float16*)alloc(Bn * 512 * 2);  // h0a -> gb
  _Float16* wsC    = (_Float16*)alloc(Bn * 640 * 2);  // feat -> x2
  _Float16* goal16 = (_Float16*)alloc(Bn * 128 * 2);
  _Float16* gate16 = (_Float16*)alloc(Bn * 128 * 2);
  _Float16* h1a16  = (_Float16*)alloc(Bn * 128 * 2);
  _Float16* wpad16 = (_Float16*)alloc(Bn * 64 * 2);
  _Float16* e0W0t  = (_Float16*)alloc((size_t)512 * 448 * 2);
  _Float16* e0W1t  = (_Float16*)alloc((size_t)512 * 512 * 2);
  _Float16* e1W0t  = (_Float16*)alloc((size_t)128 * 128 * 2);
  _Float16* e1W1t  = (_Float16*)alloc((size_t)128 * 128 * 2);
  _Float16* gW0t   = (_Float16*)alloc((size_t)512 * 128 * 2);
  _Float16* gW1t   = (_Float16*)alloc((size_t)512 * 512 * 2);
  _Float16* W0b    = (_Float16*)alloc((size_t)512 * 6464 * 2);
  _Float16* W1b    = (_Float16*)alloc((size_t)512 * 5184 * 2);
  _Float16* W2b    = (_Float16*)alloc((size_t)640 * 5184 * 2);

  dim3 blk(256);
  const int BIG = 1 << 30;

  prep_input_k<<<BATCH, blk, 0, stream>>>(input_, wsA, goal16, gate16);

  prep_wt_k<<<dim3(7, 8),    blk, 0, stream>>>(e0_W0, e0_b0, e0W0t, 400, 512, 512, 448, 1, 0);
  prep_wt_k<<<dim3(8, 8),    blk, 0, stream>>>(e0_W1, nullptr, e0W1t, 512, 512, 512, 512, 0, 0);
  prep_wt_k<<<dim3(2, 2),    blk, 0, stream>>>(e1_W0, e1_b0, e1W0t, 78, 128, 128, 128, 1, 0);
  prep_wt_k<<<dim3(2, 2),    blk, 0, stream>>>(e1_W1, nullptr, e1W1t, 128, 128, 128, 128, 0, 0);
  prep_wt_k<<<dim3(2, 8),    blk, 0, stream>>>(g_W0, g_b0, gW0t, 78, 512, 512, 128, 1, 0);
  prep_wt_k<<<dim3(8, 8),    blk, 0, stream>>>(g_W1, nullptr, gW1t, 512, 512, 512, 512, 0, 0);
  prep_wt_k<<<dim3(101, 8),  blk, 0, stream>>>(m_W0, m_b0, W0b, 6400, 512, 512, 6464, 10, 512);
  prep_wt_k<<<dim3(81, 8),   blk, 0, stream>>>(m_W1, m_b1, W1b, 5120, 512, 512, 5184, 10, 512);
  prep_wt_k<<<dim3(81, 10),  blk, 0, stream>>>(m_W2, m_b2, W2b, 5120, 578, 578, 5184, 10, 578);

  // encoder 0: pose(448) -> h0a(512) -> feat[:,0:512]
  gemm_k<false, true, false><<<dim3(256, 4), blk, 0, stream>>>(
      wsA, e0W0t, wsB, nullptr, 448, 448, 512, 7, BIG);
  gemm_k<true, true, false><<<dim3(256, 4), blk, 0, stream>>>(
      wsB, e0W1t, wsC, e0_b1, 512, 512, 640, 8, BIG);
  // encoder 1: goal(128) -> h1a(128) -> feat[:,512:640]
  gemm_k<false, true, false><<<dim3(256, 1), blk, 0, stream>>>(
      goal16, e1W0t, h1a16, nullptr, 128, 128, 128, 2, BIG);
  gemm_k<true, true, false><<<dim3(256, 1), blk, 0, stream>>>(
      h1a16, e1W1t, wsC + 512, e1_b1, 128, 128, 640, 2, BIG);
  // gating: gate(128) -> ga(512) -> gb(512) -> softmax w
  gemm_k<false, true, false><<<dim3(256, 4), blk, 0, stream>>>(
      gate16, gW0t, wsA, nullptr, 128, 128, 512, 2, BIG);
  gemm_k<true, true, false><<<dim3(256, 4), blk, 0, stream>>>(
      wsA, gW1t, wsB, g_b1, 512, 512, 512, 8, BIG);
  gate_softmax_k<<<dim3(BATCH / 64), blk, 0, stream>>>(wsB, g_W2, g_b2, wpad16);
  // experts: feat(640) -> x1(512) -> x2(512) -> pred(578)
  expert_k<10, true, false><<<dim3(256, 4), blk, 0, stream>>>(
      wsC, W0b, wsA, wpad16, 640, 6464, 512, BIG);
  expert_k<8, true, false><<<dim3(256, 4), blk, 0, stream>>>(
      wsA, W1b, wsC, wpad16, 512, 5184, 512, BIG);
  expert_k<8, false, true><<<dim3(256, 5), blk, 0, stream>>>(
      wsC, W2b, d_out, wpad16, 512, 5184, 578, 578);
}

// Round 4
// 1119.723 us; speedup vs baseline: 1.0594x; 1.0311x over previous
//
#include <hip/hip_runtime.h>
#include <math.h>

typedef _Float16 h8 __attribute__((ext_vector_type(8)));
typedef float f4 __attribute__((ext_vector_type(4)));

#define BATCH 32768

__device__ __forceinline__ void gload16(const void* g, void* l) {
  __builtin_amdgcn_global_load_lds(
      (const __attribute__((address_space(1))) unsigned int*)g,
      (__attribute__((address_space(3))) unsigned int*)l, 16, 0, 0);
}

// ---------------- prep: input slices -> fp16, padded, bias-const col ----------------
__global__ __launch_bounds__(256) void prep_input_k(const float* __restrict__ in,
    _Float16* __restrict__ pose, _Float16* __restrict__ goal, _Float16* __restrict__ gate)
{
  const int b = blockIdx.x;
  const float* r = in + (size_t)b * 556;
  for (int c = threadIdx.x; c < 448; c += 256) {
    float v = (c < 400) ? r[c] : (c == 400 ? 1.0f : 0.0f);
    pose[(size_t)b * 448 + c] = (_Float16)v;
  }
  if (threadIdx.x < 128) {
    int c = threadIdx.x;
    float v = (c < 78) ? r[400 + c] : (c == 78 ? 1.0f : 0.0f);
    goal[(size_t)b * 128 + c] = (_Float16)v;
    float v2 = (c < 78) ? r[478 + c] : (c == 78 ? 1.0f : 0.0f);
    gate[(size_t)b * 128 + c] = (_Float16)v2;
  }
}

// ---------------- prep: coalesced LDS-tiled transpose  out[n][c] <- W[c][n] ----------------
__global__ __launch_bounds__(256) void prep_wt_k(const float* __restrict__ W,
    const float* __restrict__ bias, _Float16* __restrict__ out,
    int K, int N, int Nld, int Kout, int biasCols, int biasLd)
{
  __shared__ float tile[64 * 65];
  const int t = threadIdx.x;
  const int c0 = blockIdx.x * 64;
  const int n0 = blockIdx.y * 64;
  {
    const int nn = t & 63;
    #pragma unroll
    for (int i = 0; i < 16; ++i) {
      int cc = (t >> 6) + i * 4;
      int c = c0 + cc, n = n0 + nn;
      float v = 0.0f;
      if (n < N) {
        if (c < K) v = W[(size_t)c * Nld + n];
        else if (c - K < biasCols) v = bias[(size_t)(c - K) * biasLd + n];
      }
      tile[cc * 65 + nn] = v;
    }
  }
  __syncthreads();
  {
    const int cc = t & 63;
    #pragma unroll
    for (int i = 0; i < 16; ++i) {
      int nn = (t >> 6) + i * 4;
      out[(size_t)(n0 + nn) * Kout + c0 + cc] = (_Float16)tile[cc * 65 + nn];
    }
  }
}

// ---------------- simple GEMM: 128x128 tile, BK=64, dbuf LDS, gload_lds both ----------------
template<bool EPI_BIAS, bool DO_ELU, bool OUT_F32>
__global__ __launch_bounds__(256, 2) void gemm_k(
    const _Float16* __restrict__ A, const _Float16* __restrict__ Bw,
    void* __restrict__ OutP, const float* __restrict__ bias,
    int ldA, int ldB, int ldO, int nChunks, int nLimit)
{
  __shared__ __align__(16) _Float16 As[2][128 * 64];
  __shared__ __align__(16) _Float16 Bs[2][128 * 64];

  const int t = threadIdx.x;
  const int m0 = blockIdx.x * 128;
  const int n0 = blockIdx.y * 128;
  const int wid = t >> 6;
  const int lane = t & 63;
  const int wm = (wid >> 1) * 64;
  const int wn = (wid & 1) * 64;
  const int lr = lane & 15;
  const int lg = lane >> 4;

  const int gr = lane >> 3;
  const int gcol = ((lane & 7) ^ gr) * 8;
  const _Float16* Abase = A + (size_t)(m0 + wid * 32 + gr) * ldA + gcol;
  const _Float16* Bbase = Bw + (size_t)(n0 + wid * 32 + gr) * ldB + gcol;

  f4 acc[4][4];
  #pragma unroll
  for (int i = 0; i < 4; ++i)
    #pragma unroll
    for (int j = 0; j < 4; ++j) { f4 z = {0.f, 0.f, 0.f, 0.f}; acc[i][j] = z; }

  auto issue = [&](int c, int buf) {
    #pragma unroll
    for (int i = 0; i < 4; ++i) {
      gload16(Abase + (size_t)(i * 8) * ldA + c * 64, &As[buf][(wid * 32 + i * 8) * 64]);
      gload16(Bbase + (size_t)(i * 8) * ldB + c * 64, &Bs[buf][(wid * 32 + i * 8) * 64]);
    }
  };

  auto mfma_step = [&](const _Float16* as, const _Float16* bs) {
    #pragma unroll
    for (int kk = 0; kk < 2; ++kk) {
      h8 af[4], bf[4];
      const int kslot = kk * 4 + lg;
      #pragma unroll
      for (int i = 0; i < 4; ++i) {
        const int row = wm + i * 16 + lr;
        af[i] = *reinterpret_cast<const h8*>(&as[row * 64 + ((kslot ^ (row & 7)) << 3)]);
      }
      #pragma unroll
      for (int j = 0; j < 4; ++j) {
        const int row = wn + j * 16 + lr;
        bf[j] = *reinterpret_cast<const h8*>(&bs[row * 64 + ((kslot ^ (row & 7)) << 3)]);
      }
      #pragma unroll
      for (int i = 0; i < 4; ++i)
        #pragma unroll
        for (int j = 0; j < 4; ++j)
          acc[i][j] = __builtin_amdgcn_mfma_f32_16x16x32_f16(af[i], bf[j], acc[i][j], 0, 0, 0);
    }
  };

  issue(0, 0);
  int cur = 0;
  for (int c = 0; c < nChunks; ++c) {
    __syncthreads();
    if (c + 1 < nChunks) issue(c + 1, cur ^ 1);
    mfma_step(As[cur], Bs[cur]);
    cur ^= 1;
  }

  #pragma unroll
  for (int j = 0; j < 4; ++j) {
    const int col = n0 + wn + j * 16 + lr;
    if (col >= nLimit) continue;
    float bvv = 0.0f;
    if (EPI_BIAS) bvv = bias[col];
    #pragma unroll
    for (int i = 0; i < 4; ++i) {
      const int rowb = m0 + wm + i * 16 + lg * 4;
      #pragma unroll
      for (int r = 0; r < 4; ++r) {
        float x = acc[i][j][r] + bvv;
        if (DO_ELU) x = (x > 0.0f) ? x : expm1f(x);
        if (OUT_F32)
          reinterpret_cast<float*>(OutP)[(size_t)(rowb + r) * ldO + col] = x;
        else
          reinterpret_cast<_Float16*>(OutP)[(size_t)(rowb + r) * ldO + col] = (_Float16)x;
      }
    }
  }
}

// ---------------- expert GEMM, 8-phase style: 256x256 tile, BK=32, 4-slot LDS ring ----------
// virtual K tiles: NT = E*KCe + 1 (last tile = bias blend from wpad, scale 1)
// per-tile 2 phases x 16 MFMA; stage tile t+3 during tile t; vmcnt(8) once per tile.
template<int KCe, bool DO_ELU, bool OUT_F32>
__global__ __launch_bounds__(512, 2) void expert8_k(
    const _Float16* __restrict__ A, const _Float16* __restrict__ Bw,
    void* __restrict__ OutP, const _Float16* __restrict__ wpad,
    int ldA, int ldB, int ldO, int nLimit)
{
  constexpr int E = 10;
  constexpr int NT = E * KCe + 1;
  // 4 ring slots of (A 8192 + B 8192) fp16 + gate-weight tile 256x16
  __shared__ __align__(16) _Float16 lds[4 * 16384 + 256 * 16];
  _Float16* wlds = lds + 4 * 16384;

  const int tid = threadIdx.x;
  const int w = tid >> 6;
  const int l = tid & 63;
  const int m0 = blockIdx.x * 256;
  const int n0 = blockIdx.y * 256;
  const int wrow = w >> 2;       // 0..1  -> A rows [wrow*128, +128)
  const int wcol = w & 3;        // 0..3  -> C cols [wcol*64, +64)
  const int lr = l & 15;
  const int lg = l >> 4;         // logical 16B k-slot 0..3

  // staging geometry: thread -> (row-in-half, phys slot); source col pre-swizzled
  const int stR = tid >> 2;                 // 0..127
  const int stP = tid & 3;
  const int swzc = (stR & 3) ^ ((stR >> 2) & 3);
  const int stCol = (stP ^ swzc) * 8;       // element offset within 32-wide k-window

  const _Float16* Asrc = A + (size_t)(m0 + stR) * ldA + stCol;
  const _Float16* Bsrc = Bw + (size_t)(n0 + stR) * ldB + stCol;
  const _Float16* Wsrc = wpad + (size_t)(m0 + stR) * 64 + stCol;
  const size_t AsrcH = (size_t)128 * ldA;
  const size_t BsrcH = (size_t)128 * ldB;
  const size_t WsrcH = (size_t)128 * 64;

  const int arow0 = wrow * 128 + lr;
  const int brow0 = wcol * 64 + lr;

  // swizzled fragment read: row r, logical slot lg
  auto frag = [&](const _Float16* base, int r) -> h8 {
    const int phys = lg ^ ((r & 3) ^ ((r >> 2) & 3));
    return *reinterpret_cast<const h8*>(base + r * 32 + phys * 8);
  };

  auto stageA = [&](int slot, const _Float16* src0, size_t halfStride) {
    _Float16* d = lds + slot * 16384 + (w * 16) * 32;
    gload16(src0, d);
    gload16(src0 + halfStride, d + 128 * 32);
  };
  auto stageB = [&](int slot, const _Float16* src0) {
    _Float16* d = lds + slot * 16384 + 8192 + (w * 16) * 32;
    gload16(src0, d);
    gload16(src0 + BsrcH, d + 128 * 32);
  };

  f4 acc[8][4];
  #pragma unroll
  for (int mi = 0; mi < 8; ++mi)
    #pragma unroll
    for (int ni = 0; ni < 4; ++ni) { f4 z = {0.f, 0.f, 0.f, 0.f}; acc[mi][ni] = z; }

  // ---- prologue: gate-weight tile + K-tiles 0,1,2 (e=0, kc=tt) ----
  {
    _Float16* d = wlds + w * 512;
    const _Float16* s = wpad + (size_t)(m0 + w * 32 + (l >> 1)) * 64 + (l & 1) * 8;
    gload16(s, d);
  }
  #pragma unroll
  for (int tt = 0; tt < 3; ++tt) {
    stageA(tt, Asrc + tt * 32, AsrcH);
    stageB(tt, Bsrc + tt * 32);
  }
  asm volatile("s_waitcnt vmcnt(8)" ::: "memory");   // wlds + tile 0 landed
  __builtin_amdgcn_s_barrier();
  __builtin_amdgcn_sched_barrier(0);

  int t = 0;
  #pragma unroll 1
  for (int e = 0; e < E; ++e) {
    _Float16 se[8];
    #pragma unroll
    for (int mi = 0; mi < 8; ++mi)
      se[mi] = wlds[(arow0 + mi * 16) * 16 + e];
    #pragma unroll 1
    for (int kc = 0; kc < KCe; ++kc, ++t) {
      const _Float16* As = lds + (t & 3) * 16384;
      const _Float16* Bs = As + 8192;
      const int t3 = t + 3;
      const int slot3 = t3 & 3;
      int kc3 = kc + 3; if (kc3 >= KCe) kc3 -= KCe;

      // ---------- phase 0: B frags + A frags mi 0..3, stage A halves of t+3 ----------
      h8 bf[4], aa[4];
      #pragma unroll
      for (int ni = 0; ni < 4; ++ni) bf[ni] = frag(Bs, brow0 + ni * 16);
      #pragma unroll
      for (int mi = 0; mi < 4; ++mi) aa[mi] = frag(As, arow0 + mi * 16) * se[mi];
      if (t3 < NT) {
        if (t3 == NT - 1) stageA(slot3, Wsrc, WsrcH);
        else              stageA(slot3, Asrc + kc3 * 32, AsrcH);
      }
      __builtin_amdgcn_s_barrier();
      __builtin_amdgcn_sched_barrier(0);
      __builtin_amdgcn_s_setprio(1);
      #pragma unroll
      for (int mi = 0; mi < 4; ++mi)
        #pragma unroll
        for (int ni = 0; ni < 4; ++ni)
          acc[mi][ni] = __builtin_amdgcn_mfma_f32_16x16x32_f16(aa[mi], bf[ni], acc[mi][ni], 0, 0, 0);
      __builtin_amdgcn_s_setprio(0);
      __builtin_amdgcn_s_barrier();
      __builtin_amdgcn_sched_barrier(0);

      // ---------- phase 1: A frags mi 4..7, stage B halves of t+3 ----------
      #pragma unroll
      for (int mi = 0; mi < 4; ++mi) aa[mi] = frag(As, arow0 + 64 + mi * 16) * se[4 + mi];
      if (t3 < NT) stageB(slot3, Bsrc + (size_t)t3 * 32);
      __builtin_amdgcn_s_barrier();
      __builtin_amdgcn_sched_barrier(0);
      __builtin_amdgcn_s_setprio(1);
      #pragma unroll
      for (int mi = 0; mi < 4; ++mi)
        #pragma unroll
        for (int ni = 0; ni < 4; ++ni)
          acc[4 + mi][ni] = __builtin_amdgcn_mfma_f32_16x16x32_f16(aa[mi], bf[ni], acc[4 + mi][ni], 0, 0, 0);
      __builtin_amdgcn_s_setprio(0);
      // counted drain: next tile (t+1) must be resident past this barrier
      if (t + 3 < NT)      asm volatile("s_waitcnt vmcnt(8)" ::: "memory");
      else if (t + 2 < NT) asm volatile("s_waitcnt vmcnt(4)" ::: "memory");
      else                 asm volatile("s_waitcnt vmcnt(0)" ::: "memory");
      __builtin_amdgcn_s_barrier();
      __builtin_amdgcn_sched_barrier(0);
    }
  }

  // ---- bias tile (t == NT-1): A = wpad rows, unscaled; fully resident; no staging ----
  {
    const _Float16* As = lds + (t & 3) * 16384;
    const _Float16* Bs = As + 8192;
    h8 bf[4], aa[4];
    #pragma unroll
    for (int ni = 0; ni < 4; ++ni) bf[ni] = frag(Bs, brow0 + ni * 16);
    #pragma unroll
    for (int mi = 0; mi < 4; ++mi) aa[mi] = frag(As, arow0 + mi * 16);
    #pragma unroll
    for (int mi = 0; mi < 4; ++mi)
      #pragma unroll
      for (int ni = 0; ni < 4; ++ni)
        acc[mi][ni] = __builtin_amdgcn_mfma_f32_16x16x32_f16(aa[mi], bf[ni], acc[mi][ni], 0, 0, 0);
    #pragma unroll
    for (int mi = 0; mi < 4; ++mi) aa[mi] = frag(As, arow0 + 64 + mi * 16);
    #pragma unroll
    for (int mi = 0; mi < 4; ++mi)
      #pragma unroll
      for (int ni = 0; ni < 4; ++ni)
        acc[4 + mi][ni] = __builtin_amdgcn_mfma_f32_16x16x32_f16(aa[mi], bf[ni], acc[4 + mi][ni], 0, 0, 0);
  }

  // ---- epilogue ----
  #pragma unroll
  for (int ni = 0; ni < 4; ++ni) {
    const int col = n0 + wcol * 64 + ni * 16 + lr;
    if (col >= nLimit) continue;
    #pragma unroll
    for (int mi = 0; mi < 8; ++mi) {
      const int rowb = m0 + wrow * 128 + mi * 16 + lg * 4;
      #pragma unroll
      for (int r = 0; r < 4; ++r) {
        float x = acc[mi][ni][r];
        if (DO_ELU) x = (x > 0.0f) ? x : expm1f(x);
        if (OUT_F32)
          reinterpret_cast<float*>(OutP)[(size_t)(rowb + r) * ldO + col] = x;
        else
          reinterpret_cast<_Float16*>(OutP)[(size_t)(rowb + r) * ldO + col] = (_Float16)x;
      }
    }
  }
}

// ---------------- gating final layer (N=10) + softmax -> wpad[B][64], 4 lanes/row ----------------
__global__ __launch_bounds__(256) void gate_softmax_k(const _Float16* __restrict__ gb,
    const float* __restrict__ W2, const float* __restrict__ b2, _Float16* __restrict__ wpad)
{
  __shared__ float W2s[5120];
  for (int i = threadIdx.x; i < 5120; i += 256) W2s[i] = W2[i];
  __syncthreads();
  const int t = threadIdx.x;
  const int sub = t & 3;
  const int b = blockIdx.x * 64 + (t >> 2);
  const _Float16* row = gb + (size_t)b * 512 + sub * 128;
  float acc[10];
  #pragma unroll
  for (int o = 0; o < 10; ++o) acc[o] = 0.0f;
  #pragma unroll 4
  for (int k0 = 0; k0 < 128; k0 += 8) {
    h8 x = *reinterpret_cast<const h8*>(row + k0);
    #pragma unroll
    for (int jj = 0; jj < 8; ++jj) {
      float xv = (float)x[jj];
      const int k = sub * 128 + k0 + jj;
      #pragma unroll
      for (int o = 0; o < 10; ++o) acc[o] += xv * W2s[k * 10 + o];
    }
  }
  #pragma unroll
  for (int o = 0; o < 10; ++o) {
    acc[o] += __shfl_xor(acc[o], 1);
    acc[o] += __shfl_xor(acc[o], 2);
    acc[o] += b2[o];
  }
  float mx = acc[0];
  #pragma unroll
  for (int o = 1; o < 10; ++o) mx = fmaxf(mx, acc[o]);
  float s = 0.0f;
  #pragma unroll
  for (int o = 0; o < 10; ++o) { acc[o] = expf(acc[o] - mx); s += acc[o]; }
  const float inv = 1.0f / s;
  h8 o0 = {0,0,0,0,0,0,0,0}, o1 = {0,0,0,0,0,0,0,0};
  if (sub == 0) {
    #pragma unroll
    for (int o = 0; o < 8; ++o) o0[o] = (_Float16)(acc[o] * inv);
    o1[0] = (_Float16)(acc[8] * inv);
    o1[1] = (_Float16)(acc[9] * inv);
  }
  _Float16* wr = wpad + (size_t)b * 64 + sub * 16;
  *reinterpret_cast<h8*>(wr) = o0;
  *reinterpret_cast<h8*>(wr + 8) = o1;
}

extern "C" void kernel_launch(void* const* d_in, const int* in_sizes, int n_in,
                              void* d_out, int out_size, void* d_ws, size_t ws_size,
                              hipStream_t stream)
{
  const float* input_ = (const float*)d_in[0];
  const float* e0_W0 = (const float*)d_in[1];
  const float* e0_b0 = (const float*)d_in[2];
  const float* e0_W1 = (const float*)d_in[3];
  const float* e0_b1 = (const float*)d_in[4];
  const float* e1_W0 = (const float*)d_in[5];
  const float* e1_b0 = (const float*)d_in[6];
  const float* e1_W1 = (const float*)d_in[7];
  const float* e1_b1 = (const float*)d_in[8];
  const float* g_W0  = (const float*)d_in[9];
  const float* g_b0  = (const float*)d_in[10];
  const float* g_W1  = (const float*)d_in[11];
  const float* g_b1  = (const float*)d_in[12];
  const float* g_W2  = (const float*)d_in[13];
  const float* g_b2  = (const float*)d_in[14];
  const float* m_W0  = (const float*)d_in[15];
  const float* m_b0  = (const float*)d_in[16];
  const float* m_W1  = (const float*)d_in[17];
  const float* m_b1  = (const float*)d_in[18];
  const float* m_W2  = (const float*)d_in[19];
  const float* m_b2  = (const float*)d_in[20];
  (void)in_sizes; (void)n_in; (void)out_size; (void)ws_size;

  char* ws = (char*)d_ws;
  size_t off = 0;
  auto alloc = [&](size_t bytes) { char* p = ws + off; off += (bytes + 255) & ~(size_t)255; return p; };

  const size_t Bn = BATCH;
  _Float16* wsA    = (_Float16*)alloc(Bn * 512 * 2);  // pose16[448] -> ga16 -> x1
  _Float16* wsB    = (_Float16*)alloc(Bn * 512 * 2);  // h0a -> gb
  _Float16* wsC    = (_Float16*)alloc(Bn * 640 * 2);  // feat -> x2
  _Float16* goal16 = (_Float16*)alloc(Bn * 128 * 2);
  _Float16* gate16 = (_Float16*)alloc(Bn * 128 * 2);
  _Float16* h1a16  = (_Float16*)alloc(Bn * 128 * 2);
  _Float16* wpad16 = (_Float16*)alloc(Bn * 64 * 2);
  _Float16* e0W0t  = (_Float16*)alloc((size_t)512 * 448 * 2);
  _Float16* e0W1t  = (_Float16*)alloc((size_t)512 * 512 * 2);
  _Float16* e1W0t  = (_Float16*)alloc((size_t)128 * 128 * 2);
  _Float16* e1W1t  = (_Float16*)alloc((size_t)128 * 128 * 2);
  _Float16* gW0t   = (_Float16*)alloc((size_t)512 * 128 * 2);
  _Float16* gW1t   = (_Float16*)alloc((size_t)512 * 512 * 2);
  _Float16* W0b    = (_Float16*)alloc((size_t)512 * 6464 * 2);
  _Float16* W1b    = (_Float16*)alloc((size_t)512 * 5184 * 2);
  _Float16* W2b    = (_Float16*)alloc((size_t)768 * 5184 * 2);

  dim3 blk(256);
  const int BIG = 1 << 30;

  prep_input_k<<<BATCH, blk, 0, stream>>>(input_, wsA, goal16, gate16);

  prep_wt_k<<<dim3(7, 8),    blk, 0, stream>>>(e0_W0, e0_b0, e0W0t, 400, 512, 512, 448, 1, 0);
  prep_wt_k<<<dim3(8, 8),    blk, 0, stream>>>(e0_W1, nullptr, e0W1t, 512, 512, 512, 512, 0, 0);
  prep_wt_k<<<dim3(2, 2),    blk, 0, stream>>>(e1_W0, e1_b0, e1W0t, 78, 128, 128, 128, 1, 0);
  prep_wt_k<<<dim3(2, 2),    blk, 0, stream>>>(e1_W1, nullptr, e1W1t, 128, 128, 128, 128, 0, 0);
  prep_wt_k<<<dim3(2, 8),    blk, 0, stream>>>(g_W0, g_b0, gW0t, 78, 512, 512, 128, 1, 0);
  prep_wt_k<<<dim3(8, 8),    blk, 0, stream>>>(g_W1, nullptr, gW1t, 512, 512, 512, 512, 0, 0);
  prep_wt_k<<<dim3(101, 8),  blk, 0, stream>>>(m_W0, m_b0, W0b, 6400, 512, 512, 6464, 10, 512);
  prep_wt_k<<<dim3(81, 8),   blk, 0, stream>>>(m_W1, m_b1, W1b, 5120, 512, 512, 5184, 10, 512);
  prep_wt_k<<<dim3(81, 12),  blk, 0, stream>>>(m_W2, m_b2, W2b, 5120, 578, 578, 5184, 10, 578);

  // encoder 0: pose(448) -> h0a(512) -> feat[:,0:512]
  gemm_k<false, true, false><<<dim3(256, 4), blk, 0, stream>>>(
      wsA, e0W0t, wsB, nullptr, 448, 448, 512, 7, BIG);
  gemm_k<true, true, false><<<dim3(256, 4), blk, 0, stream>>>(
      wsB, e0W1t, wsC, e0_b1, 512, 512, 640, 8, BIG);
  // encoder 1: goal(128) -> h1a(128) -> feat[:,512:640]
  gemm_k<false, true, false><<<dim3(256, 1), blk, 0, stream>>>(
      goal16, e1W0t, h1a16, nullptr, 128, 128, 128, 2, BIG);
  gemm_k<true, true, false><<<dim3(256, 1), blk, 0, stream>>>(
      h1a16, e1W1t, wsC + 512, e1_b1, 128, 128, 640, 2, BIG);
  // gating: gate(128) -> ga(512) -> gb(512) -> softmax w
  gemm_k<false, true, false><<<dim3(256, 4), blk, 0, stream>>>(
      gate16, gW0t, wsA, nullptr, 128, 128, 512, 2, BIG);
  gemm_k<true, true, false><<<dim3(256, 4), blk, 0, stream>>>(
      wsA, gW1t, wsB, g_b1, 512, 512, 512, 8, BIG);
  gate_softmax_k<<<dim3(BATCH / 64), blk, 0, stream>>>(wsB, g_W2, g_b2, wpad16);

  // experts (8-phase 256x256): feat(640) -> x1(512) -> x2(512) -> pred(578)
  expert8_k<20, true, false><<<dim3(128, 2), dim3(512), 0, stream>>>(
      wsC, W0b, wsA, wpad16, 640, 6464, 512, BIG);
  expert8_k<16, true, false><<<dim3(128, 2), dim3(512), 0, stream>>>(
      wsA, W1b, wsC, wpad16, 512, 5184, 512, BIG);
  expert8_k<16, false, true><<<dim3(128, 3), dim3(512), 0, stream>>>(
      wsC, W2b, d_out, wpad16, 512, 5184, 578, 578);
}

// Round 5
// 1049.539 us; speedup vs baseline: 1.1303x; 1.0669x over previous
//
#include <hip/hip_runtime.h>
#include <math.h>

typedef _Float16 h8 __attribute__((ext_vector_type(8)));
typedef float f4 __attribute__((ext_vector_type(4)));

#define BATCH 32768

__device__ __forceinline__ void gload16(const void* g, void* l) {
  __builtin_amdgcn_global_load_lds(
      (const __attribute__((address_space(1))) unsigned int*)g,
      (__attribute__((address_space(3))) unsigned int*)l, 16, 0, 0);
}

// ---------------- prep: input slices -> fp16, padded, bias-const col ----------------
__global__ __launch_bounds__(256) void prep_input_k(const float* __restrict__ in,
    _Float16* __restrict__ pose, _Float16* __restrict__ goal, _Float16* __restrict__ gate)
{
  const int b = blockIdx.x;
  const float* r = in + (size_t)b * 556;
  for (int c = threadIdx.x; c < 448; c += 256) {
    float v = (c < 400) ? r[c] : (c == 400 ? 1.0f : 0.0f);
    pose[(size_t)b * 448 + c] = (_Float16)v;
  }
  if (threadIdx.x < 128) {
    int c = threadIdx.x;
    float v = (c < 78) ? r[400 + c] : (c == 78 ? 1.0f : 0.0f);
    goal[(size_t)b * 128 + c] = (_Float16)v;
    float v2 = (c < 78) ? r[478 + c] : (c == 78 ? 1.0f : 0.0f);
    gate[(size_t)b * 128 + c] = (_Float16)v2;
  }
}

// ---------------- prep: coalesced LDS-tiled transpose  out[n][c] <- W[c][n] ----------------
__global__ __launch_bounds__(256) void prep_wt_k(const float* __restrict__ W,
    const float* __restrict__ bias, _Float16* __restrict__ out,
    int K, int N, int Nld, int Kout, int biasCols, int biasLd)
{
  __shared__ float tile[64 * 65];
  const int t = threadIdx.x;
  const int c0 = blockIdx.x * 64;
  const int n0 = blockIdx.y * 64;
  {
    const int nn = t & 63;
    #pragma unroll
    for (int i = 0; i < 16; ++i) {
      int cc = (t >> 6) + i * 4;
      int c = c0 + cc, n = n0 + nn;
      float v = 0.0f;
      if (n < N) {
        if (c < K) v = W[(size_t)c * Nld + n];
        else if (c - K < biasCols) v = bias[(size_t)(c - K) * biasLd + n];
      }
      tile[cc * 65 + nn] = v;
    }
  }
  __syncthreads();
  {
    const int cc = t & 63;
    #pragma unroll
    for (int i = 0; i < 16; ++i) {
      int nn = (t >> 6) + i * 4;
      out[(size_t)(n0 + nn) * Kout + c0 + cc] = (_Float16)tile[cc * 65 + nn];
    }
  }
}

// ---------------- simple GEMM: 128x128 tile, BK=64, dbuf LDS, gload_lds both ----------------
template<bool EPI_BIAS, bool DO_ELU, bool OUT_F32>
__global__ __launch_bounds__(256, 2) void gemm_k(
    const _Float16* __restrict__ A, const _Float16* __restrict__ Bw,
    void* __restrict__ OutP, const float* __restrict__ bias,
    int ldA, int ldB, int ldO, int nChunks, int nLimit)
{
  __shared__ __align__(16) _Float16 As[2][128 * 64];
  __shared__ __align__(16) _Float16 Bs[2][128 * 64];

  const int t = threadIdx.x;
  const int m0 = blockIdx.x * 128;
  const int n0 = blockIdx.y * 128;
  const int wid = t >> 6;
  const int lane = t & 63;
  const int wm = (wid >> 1) * 64;
  const int wn = (wid & 1) * 64;
  const int lr = lane & 15;
  const int lg = lane >> 4;

  const int gr = lane >> 3;
  const int gcol = ((lane & 7) ^ gr) * 8;
  const _Float16* Abase = A + (size_t)(m0 + wid * 32 + gr) * ldA + gcol;
  const _Float16* Bbase = Bw + (size_t)(n0 + wid * 32 + gr) * ldB + gcol;

  f4 acc[4][4];
  #pragma unroll
  for (int i = 0; i < 4; ++i)
    #pragma unroll
    for (int j = 0; j < 4; ++j) { f4 z = {0.f, 0.f, 0.f, 0.f}; acc[i][j] = z; }

  auto issue = [&](int c, int buf) {
    #pragma unroll
    for (int i = 0; i < 4; ++i) {
      gload16(Abase + (size_t)(i * 8) * ldA + c * 64, &As[buf][(wid * 32 + i * 8) * 64]);
      gload16(Bbase + (size_t)(i * 8) * ldB + c * 64, &Bs[buf][(wid * 32 + i * 8) * 64]);
    }
  };

  auto mfma_step = [&](const _Float16* as, const _Float16* bs) {
    #pragma unroll
    for (int kk = 0; kk < 2; ++kk) {
      h8 af[4], bf[4];
      const int kslot = kk * 4 + lg;
      #pragma unroll
      for (int i = 0; i < 4; ++i) {
        const int row = wm + i * 16 + lr;
        af[i] = *reinterpret_cast<const h8*>(&as[row * 64 + ((kslot ^ (row & 7)) << 3)]);
      }
      #pragma unroll
      for (int j = 0; j < 4; ++j) {
        const int row = wn + j * 16 + lr;
        bf[j] = *reinterpret_cast<const h8*>(&bs[row * 64 + ((kslot ^ (row & 7)) << 3)]);
      }
      #pragma unroll
      for (int i = 0; i < 4; ++i)
        #pragma unroll
        for (int j = 0; j < 4; ++j)
          acc[i][j] = __builtin_amdgcn_mfma_f32_16x16x32_f16(af[i], bf[j], acc[i][j], 0, 0, 0);
    }
  };

  issue(0, 0);
  int cur = 0;
  for (int c = 0; c < nChunks; ++c) {
    __syncthreads();
    if (c + 1 < nChunks) issue(c + 1, cur ^ 1);
    mfma_step(As[cur], Bs[cur]);
    cur ^= 1;
  }

  #pragma unroll
  for (int j = 0; j < 4; ++j) {
    const int col = n0 + wn + j * 16 + lr;
    if (col >= nLimit) continue;
    float bvv = 0.0f;
    if (EPI_BIAS) bvv = bias[col];
    #pragma unroll
    for (int i = 0; i < 4; ++i) {
      const int rowb = m0 + wm + i * 16 + lg * 4;
      #pragma unroll
      for (int r = 0; r < 4; ++r) {
        float x = acc[i][j][r] + bvv;
        if (DO_ELU) x = (x > 0.0f) ? x : expm1f(x);
        if (OUT_F32)
          reinterpret_cast<float*>(OutP)[(size_t)(rowb + r) * ldO + col] = x;
        else
          reinterpret_cast<_Float16*>(OutP)[(size_t)(rowb + r) * ldO + col] = (_Float16)x;
      }
    }
  }
}

// ---------------- expert GEMM: 128x256 tile, BK=64, ring-3 LDS, counted vmcnt ----------
// virtual K tiles t = e*KCe + kc, NT = E*KCe + 1 (last = bias blend from wpad).
// Stage tile t+2 during tile t (slot (t+2)%3); one vmcnt(6) per tile boundary.
// LDS slot: A[128][64] (8192 el) + B[256][64] (16384 el) = 24576 el; rows 128B,
// 16B slot s stored at phys (s ^ (row&7)) via pre-swizzled global source (R3-proven, 0-conflict).
template<int KCe, bool DO_ELU, bool OUT_F32>
__global__ __launch_bounds__(512, 2) void expert9_k(
    const _Float16* __restrict__ A, const _Float16* __restrict__ Bw,
    void* __restrict__ OutP, const _Float16* __restrict__ wpad,
    int ldA, int ldB, int ldO, int nLimit)
{
  constexpr int E = 10;
  constexpr int NT = E * KCe + 1;
  constexpr int SLOT = 24576;
  __shared__ __align__(16) _Float16 lds[3 * SLOT + 128 * 32];
  _Float16* wlds = lds + 3 * SLOT;

  const int tid = threadIdx.x;
  const int w = tid >> 6;
  const int l = tid & 63;
  const int m0 = blockIdx.x * 128;
  const int n0 = blockIdx.y * 256;
  const int wrow = w >> 2;          // 0..1 -> A rows [wrow*64, +64)
  const int wcol = w & 3;           // 0..3 -> B rows [wcol*64, +64)
  const int lr = l & 15;
  const int lg = l >> 4;

  // staging geometry: thread row = tid>>3, slot s = tid&7; source col pre-swizzled
  const int strow = tid >> 3;
  const int swzcol = ((tid & 7) ^ (strow & 7)) * 8;
  const _Float16* Astg = A + (size_t)(m0 + strow) * ldA + swzcol;
  const _Float16* Bstg = Bw + (size_t)(n0 + strow) * ldB + swzcol;
  const _Float16* Wstg = wpad + (size_t)(m0 + strow) * 64 + swzcol;

  const int arow0 = wrow * 64 + lr;
  const int brow0 = wcol * 64 + lr;

  auto frag = [&](const _Float16* base, int row, int kslot) -> h8 {
    return *reinterpret_cast<const h8*>(base + row * 64 + ((kslot ^ (row & 7)) << 3));
  };

  // A tile stage: 2 gloads (rows strow, strow+64); wave-uniform LDS base
  auto stA = [&](int slot, const _Float16* src, size_t rstride) {
    _Float16* d = lds + slot * SLOT + w * 512;
    gload16(src, d);
    gload16(src + 64 * rstride, d + 4096);
  };
  // B tile stage: 4 gloads (rows strow + 64k)
  auto stB1 = [&](int slot, const _Float16* src) {
    _Float16* d = lds + slot * SLOT + 8192 + w * 512;
    gload16(src, d);
  };
  auto stB3 = [&](int slot, const _Float16* src) {
    _Float16* d = lds + slot * SLOT + 8192 + w * 512;
    gload16(src + (size_t)64 * ldB, d + 4096);
    gload16(src + (size_t)128 * ldB, d + 8192);
    gload16(src + (size_t)192 * ldB, d + 12288);
  };

  f4 acc[4][4];
  #pragma unroll
  for (int mi = 0; mi < 4; ++mi)
    #pragma unroll
    for (int ni = 0; ni < 4; ++ni) { f4 z = {0.f, 0.f, 0.f, 0.f}; acc[mi][ni] = z; }

  // ---- prologue: wlds (1 load) + tiles 0,1,2 (6 loads each) ----
  {
    // gate tile: 128 rows x 32 cols of wpad (cols >=10 junk, unused)
    const _Float16* s = wpad + (size_t)(m0 + (tid >> 2)) * 64 + (tid & 3) * 8;
    gload16(s, wlds + w * 512);
  }
  #pragma unroll
  for (int tt = 0; tt < 3; ++tt) {
    stA(tt, Astg + tt * 64, (size_t)ldA);
    stB1(tt, Bstg + tt * 64);
    stB3(tt, Bstg + tt * 64);
  }
  asm volatile("s_waitcnt vmcnt(12)" ::: "memory");   // wlds + tile0 resident
  __builtin_amdgcn_s_barrier();
  __builtin_amdgcn_sched_barrier(0);

  int t = 0, slc = 0, sls = 2;   // compute slot, stage slot ((t+2)%3)
  #pragma unroll 1
  for (int e = 0; e < E; ++e) {
    _Float16 se[4];
    #pragma unroll
    for (int mi = 0; mi < 4; ++mi)
      se[mi] = wlds[(arow0 + mi * 16) * 32 + e];
    #pragma unroll 1
    for (int kc = 0; kc < KCe; ++kc, ++t) {
      const _Float16* As = lds + slc * SLOT;
      const _Float16* Bs = As + 8192;
      const int u = t + 2;
      int kcu = kc + 2; if (kcu >= KCe) kcu -= KCe;

      // ---- phase 0 (kk=0): frags + stage A(2)+B(1) of tile u ----
      h8 bf[4], aa[4];
      #pragma unroll
      for (int ni = 0; ni < 4; ++ni) bf[ni] = frag(Bs, brow0 + ni * 16, lg);
      #pragma unroll
      for (int mi = 0; mi < 4; ++mi) aa[mi] = frag(As, arow0 + mi * 16, lg) * se[mi];
      if (u < NT - 1) {
        stA(sls, Astg + kcu * 64, (size_t)ldA);
        stB1(sls, Bstg + (size_t)u * 64);
      } else if (u == NT - 1) {
        stA(sls, Wstg, (size_t)64);
        stB1(sls, Bstg + (size_t)u * 64);
      }
      __builtin_amdgcn_s_barrier();
      __builtin_amdgcn_sched_barrier(0);
      __builtin_amdgcn_s_setprio(1);
      #pragma unroll
      for (int mi = 0; mi < 4; ++mi)
        #pragma unroll
        for (int ni = 0; ni < 4; ++ni)
          acc[mi][ni] = __builtin_amdgcn_mfma_f32_16x16x32_f16(aa[mi], bf[ni], acc[mi][ni], 0, 0, 0);
      __builtin_amdgcn_s_setprio(0);
      __builtin_amdgcn_s_barrier();
      __builtin_amdgcn_sched_barrier(0);

      // ---- phase 1 (kk=1): frags + stage B(3) of tile u ----
      #pragma unroll
      for (int ni = 0; ni < 4; ++ni) bf[ni] = frag(Bs, brow0 + ni * 16, 4 + lg);
      #pragma unroll
      for (int mi = 0; mi < 4; ++mi) aa[mi] = frag(As, arow0 + mi * 16, 4 + lg) * se[mi];
      if (u <= NT - 1) stB3(sls, Bstg + (size_t)u * 64);
      __builtin_amdgcn_s_barrier();
      __builtin_amdgcn_sched_barrier(0);
      __builtin_amdgcn_s_setprio(1);
      #pragma unroll
      for (int mi = 0; mi < 4; ++mi)
        #pragma unroll
        for (int ni = 0; ni < 4; ++ni)
          acc[mi][ni] = __builtin_amdgcn_mfma_f32_16x16x32_f16(aa[mi], bf[ni], acc[mi][ni], 0, 0, 0);
      __builtin_amdgcn_s_setprio(0);
      // ---- tile boundary: counted drain (tile t+1 must be resident) ----
      __builtin_amdgcn_sched_barrier(0);
      if (u <= NT - 1) asm volatile("s_waitcnt vmcnt(6)" ::: "memory");
      else             asm volatile("s_waitcnt vmcnt(0)" ::: "memory");
      __builtin_amdgcn_s_barrier();
      __builtin_amdgcn_sched_barrier(0);
      slc = (slc == 2) ? 0 : slc + 1;
      sls = (sls == 2) ? 0 : sls + 1;
    }
  }

  // ---- bias tile (t = NT-1): A = wpad rows, unscaled; fully resident ----
  {
    const _Float16* As = lds + slc * SLOT;
    const _Float16* Bs = As + 8192;
    #pragma unroll
    for (int kk = 0; kk < 2; ++kk) {
      h8 bf[4], aa[4];
      #pragma unroll
      for (int ni = 0; ni < 4; ++ni) bf[ni] = frag(Bs, brow0 + ni * 16, kk * 4 + lg);
      #pragma unroll
      for (int mi = 0; mi < 4; ++mi) aa[mi] = frag(As, arow0 + mi * 16, kk * 4 + lg);
      #pragma unroll
      for (int mi = 0; mi < 4; ++mi)
        #pragma unroll
        for (int ni = 0; ni < 4; ++ni)
          acc[mi][ni] = __builtin_amdgcn_mfma_f32_16x16x32_f16(aa[mi], bf[ni], acc[mi][ni], 0, 0, 0);
    }
  }

  // ---- epilogue ----
  #pragma unroll
  for (int ni = 0; ni < 4; ++ni) {
    const int col = n0 + wcol * 64 + ni * 16 + lr;
    if (col >= nLimit) continue;
    #pragma unroll
    for (int mi = 0; mi < 4; ++mi) {
      const int rowb = m0 + wrow * 64 + mi * 16 + lg * 4;
      #pragma unroll
      for (int r = 0; r < 4; ++r) {
        float x = acc[mi][ni][r];
        if (DO_ELU) x = (x > 0.0f) ? x : expm1f(x);
        if (OUT_F32)
          reinterpret_cast<float*>(OutP)[(size_t)(rowb + r) * ldO + col] = x;
        else
          reinterpret_cast<_Float16*>(OutP)[(size_t)(rowb + r) * ldO + col] = (_Float16)x;
      }
    }
  }
}

// ---------------- gating final layer (N=10) + softmax -> wpad[B][64], 4 lanes/row ----------------
__global__ __launch_bounds__(256) void gate_softmax_k(const _Float16* __restrict__ gb,
    const float* __restrict__ W2, const float* __restrict__ b2, _Float16* __restrict__ wpad)
{
  __shared__ float W2s[5120];
  for (int i = threadIdx.x; i < 5120; i += 256) W2s[i] = W2[i];
  __syncthreads();
  const int t = threadIdx.x;
  const int sub = t & 3;
  const int b = blockIdx.x * 64 + (t >> 2);
  const _Float16* row = gb + (size_t)b * 512 + sub * 128;
  float acc[10];
  #pragma unroll
  for (int o = 0; o < 10; ++o) acc[o] = 0.0f;
  #pragma unroll 4
  for (int k0 = 0; k0 < 128; k0 += 8) {
    h8 x = *reinterpret_cast<const h8*>(row + k0);
    #pragma unroll
    for (int jj = 0; jj < 8; ++jj) {
      float xv = (float)x[jj];
      const int k = sub * 128 + k0 + jj;
      #pragma unroll
      for (int o = 0; o < 10; ++o) acc[o] += xv * W2s[k * 10 + o];
    }
  }
  #pragma unroll
  for (int o = 0; o < 10; ++o) {
    acc[o] += __shfl_xor(acc[o], 1);
    acc[o] += __shfl_xor(acc[o], 2);
    acc[o] += b2[o];
  }
  float mx = acc[0];
  #pragma unroll
  for (int o = 1; o < 10; ++o) mx = fmaxf(mx, acc[o]);
  float s = 0.0f;
  #pragma unroll
  for (int o = 0; o < 10; ++o) { acc[o] = expf(acc[o] - mx); s += acc[o]; }
  const float inv = 1.0f / s;
  h8 o0 = {0,0,0,0,0,0,0,0}, o1 = {0,0,0,0,0,0,0,0};
  if (sub == 0) {
    #pragma unroll
    for (int o = 0; o < 8; ++o) o0[o] = (_Float16)(acc[o] * inv);
    o1[0] = (_Float16)(acc[8] * inv);
    o1[1] = (_Float16)(acc[9] * inv);
  }
  _Float16* wr = wpad + (size_t)b * 64 + sub * 16;
  *reinterpret_cast<h8*>(wr) = o0;
  *reinterpret_cast<h8*>(wr + 8) = o1;
}

extern "C" void kernel_launch(void* const* d_in, const int* in_sizes, int n_in,
                              void* d_out, int out_size, void* d_ws, size_t ws_size,
                              hipStream_t stream)
{
  const float* input_ = (const float*)d_in[0];
  const float* e0_W0 = (const float*)d_in[1];
  const float* e0_b0 = (const float*)d_in[2];
  const float* e0_W1 = (const float*)d_in[3];
  const float* e0_b1 = (const float*)d_in[4];
  const float* e1_W0 = (const float*)d_in[5];
  const float* e1_b0 = (const float*)d_in[6];
  const float* e1_W1 = (const float*)d_in[7];
  const float* e1_b1 = (const float*)d_in[8];
  const float* g_W0  = (const float*)d_in[9];
  const float* g_b0  = (const float*)d_in[10];
  const float* g_W1  = (const float*)d_in[11];
  const float* g_b1  = (const float*)d_in[12];
  const float* g_W2  = (const float*)d_in[13];
  const float* g_b2  = (const float*)d_in[14];
  const float* m_W0  = (const float*)d_in[15];
  const float* m_b0  = (const float*)d_in[16];
  const float* m_W1  = (const float*)d_in[17];
  const float* m_b1  = (const float*)d_in[18];
  const float* m_W2  = (const float*)d_in[19];
  const float* m_b2  = (const float*)d_in[20];
  (void)in_sizes; (void)n_in; (void)out_size; (void)ws_size;

  char* ws = (char*)d_ws;
  size_t off = 0;
  auto alloc = [&](size_t bytes) { char* p = ws + off; off += (bytes + 255) & ~(size_t)255; return p; };

  const size_t Bn = BATCH;
  _Float16* wsA    = (_Float16*)alloc(Bn * 512 * 2);  // pose16[448] -> ga16 -> x1
  _Float16* wsB    = (_Float16*)alloc(Bn * 512 * 2);  // h0a -> gb
  _Float16* wsC    = (_Float16*)alloc(Bn * 640 * 2);  // feat -> x2
  _Float16* goal16 = (_Float16*)alloc(Bn * 128 * 2);
  _Float16* gate16 = (_Float16*)alloc(Bn * 128 * 2);
  _Float16* h1a16  = (_Float16*)alloc(Bn * 128 * 2);
  _Float16* wpad16 = (_Float16*)alloc(Bn * 64 * 2);
  _Float16* e0W0t  = (_Float16*)alloc((size_t)512 * 448 * 2);
  _Float16* e0W1t  = (_Float16*)alloc((size_t)512 * 512 * 2);
  _Float16* e1W0t  = (_Float16*)alloc((size_t)128 * 128 * 2);
  _Float16* e1W1t  = (_Float16*)alloc((size_t)128 * 128 * 2);
  _Float16* gW0t   = (_Float16*)alloc((size_t)512 * 128 * 2);
  _Float16* gW1t   = (_Float16*)alloc((size_t)512 * 512 * 2);
  _Float16* W0b    = (_Float16*)alloc((size_t)512 * 6464 * 2);
  _Float16* W1b    = (_Float16*)alloc((size_t)512 * 5184 * 2);
  _Float16* W2b    = (_Float16*)alloc((size_t)768 * 5184 * 2);

  dim3 blk(256);
  const int BIG = 1 << 30;

  prep_input_k<<<BATCH, blk, 0, stream>>>(input_, wsA, goal16, gate16);

  prep_wt_k<<<dim3(7, 8),    blk, 0, stream>>>(e0_W0, e0_b0, e0W0t, 400, 512, 512, 448, 1, 0);
  prep_wt_k<<<dim3(8, 8),    blk, 0, stream>>>(e0_W1, nullptr, e0W1t, 512, 512, 512, 512, 0, 0);
  prep_wt_k<<<dim3(2, 2),    blk, 0, stream>>>(e1_W0, e1_b0, e1W0t, 78, 128, 128, 128, 1, 0);
  prep_wt_k<<<dim3(2, 2),    blk, 0, stream>>>(e1_W1, nullptr, e1W1t, 128, 128, 128, 128, 0, 0);
  prep_wt_k<<<dim3(2, 8),    blk, 0, stream>>>(g_W0, g_b0, gW0t, 78, 512, 512, 128, 1, 0);
  prep_wt_k<<<dim3(8, 8),    blk, 0, stream>>>(g_W1, nullptr, gW1t, 512, 512, 512, 512, 0, 0);
  prep_wt_k<<<dim3(101, 8),  blk, 0, stream>>>(m_W0, m_b0, W0b, 6400, 512, 512, 6464, 10, 512);
  prep_wt_k<<<dim3(81, 8),   blk, 0, stream>>>(m_W1, m_b1, W1b, 5120, 512, 512, 5184, 10, 512);
  prep_wt_k<<<dim3(81, 12),  blk, 0, stream>>>(m_W2, m_b2, W2b, 5120, 578, 578, 5184, 10, 578);

  // encoder 0: pose(448) -> h0a(512) -> feat[:,0:512]
  gemm_k<false, true, false><<<dim3(256, 4), blk, 0, stream>>>(
      wsA, e0W0t, wsB, nullptr, 448, 448, 512, 7, BIG);
  gemm_k<true, true, false><<<dim3(256, 4), blk, 0, stream>>>(
      wsB, e0W1t, wsC, e0_b1, 512, 512, 640, 8, BIG);
  // encoder 1: goal(128) -> h1a(128) -> feat[:,512:640]
  gemm_k<false, true, false><<<dim3(256, 1), blk, 0, stream>>>(
      goal16, e1W0t, h1a16, nullptr, 128, 128, 128, 2, BIG);
  gemm_k<true, true, false><<<dim3(256, 1), blk, 0, stream>>>(
      h1a16, e1W1t, wsC + 512, e1_b1, 128, 128, 640, 2, BIG);
  // gating: gate(128) -> ga(512) -> gb(512) -> softmax w
  gemm_k<false, true, false><<<dim3(256, 4), blk, 0, stream>>>(
      gate16, gW0t, wsA, nullptr, 128, 128, 512, 2, BIG);
  gemm_k<true, true, false><<<dim3(256, 4), blk, 0, stream>>>(
      wsA, gW1t, wsB, g_b1, 512, 512, 512, 8, BIG);
  gate_softmax_k<<<dim3(BATCH / 64), blk, 0, stream>>>(wsB, g_W2, g_b2, wpad16);

  // experts (ring-3 128x256): feat(640) -> x1(512) -> x2(512) -> pred(578)
  expert9_k<10, true, false><<<dim3(256, 2), dim3(512), 0, stream>>>(
      wsC, W0b, wsA, wpad16, 640, 6464, 512, BIG);
  expert9_k<8, true, false><<<dim3(256, 2), dim3(512), 0, stream>>>(
      wsA, W1b, wsC, wpad16, 512, 5184, 512, BIG);
  expert9_k<8, false, true><<<dim3(256, 3), dim3(512), 0, stream>>>(
      wsC, W2b, d_out, wpad16, 512, 5184, 578, 578);
}

// Round 7
// 1019.741 us; speedup vs baseline: 1.1633x; 1.0292x over previous
//
#include <hip/hip_runtime.h>
#include <math.h>

typedef _Float16 h8 __attribute__((ext_vector_type(8)));
typedef float f4 __attribute__((ext_vector_type(4)));

#define BATCH 32768

__device__ __forceinline__ void gload16(const void* g, void* l) {
  __builtin_amdgcn_global_load_lds(
      (const __attribute__((address_space(1))) unsigned int*)g,
      (__attribute__((address_space(3))) unsigned int*)l, 16, 0, 0);
}

// ---------------- prep: input slices -> fp16, padded, bias-const col ----------------
__global__ __launch_bounds__(256) void prep_input_k(const float* __restrict__ in,
    _Float16* __restrict__ pose, _Float16* __restrict__ goal, _Float16* __restrict__ gate)
{
  const int b = blockIdx.x;
  const float* r = in + (size_t)b * 556;
  for (int c = threadIdx.x; c < 448; c += 256) {
    float v = (c < 400) ? r[c] : (c == 400 ? 1.0f : 0.0f);
    pose[(size_t)b * 448 + c] = (_Float16)v;
  }
  if (threadIdx.x < 128) {
    int c = threadIdx.x;
    float v = (c < 78) ? r[400 + c] : (c == 78 ? 1.0f : 0.0f);
    goal[(size_t)b * 128 + c] = (_Float16)v;
    float v2 = (c < 78) ? r[478 + c] : (c == 78 ? 1.0f : 0.0f);
    gate[(size_t)b * 128 + c] = (_Float16)v2;
  }
}

// ---------------- prep: coalesced LDS-tiled transpose  out[n][c] <- W[c][n] ----------------
__global__ __launch_bounds__(256) void prep_wt_k(const float* __restrict__ W,
    const float* __restrict__ bias, _Float16* __restrict__ out,
    int K, int N, int Nld, int Kout, int biasCols, int biasLd)
{
  __shared__ float tile[64 * 65];
  const int t = threadIdx.x;
  const int c0 = blockIdx.x * 64;
  const int n0 = blockIdx.y * 64;
  {
    const int nn = t & 63;
    #pragma unroll
    for (int i = 0; i < 16; ++i) {
      int cc = (t >> 6) + i * 4;
      int c = c0 + cc, n = n0 + nn;
      float v = 0.0f;
      if (n < N) {
        if (c < K) v = W[(size_t)c * Nld + n];
        else if (c - K < biasCols) v = bias[(size_t)(c - K) * biasLd + n];
      }
      tile[cc * 65 + nn] = v;
    }
  }
  __syncthreads();
  {
    const int cc = t & 63;
    #pragma unroll
    for (int i = 0; i < 16; ++i) {
      int nn = (t >> 6) + i * 4;
      out[(size_t)(n0 + nn) * Kout + c0 + cc] = (_Float16)tile[cc * 65 + nn];
    }
  }
}

// ---------------- simple GEMM: 128x128 tile, BK=64, dbuf LDS, gload_lds both ----------------
template<bool EPI_BIAS, bool DO_ELU, bool OUT_F32>
__global__ __launch_bounds__(256, 2) void gemm_k(
    const _Float16* __restrict__ A, const _Float16* __restrict__ Bw,
    void* __restrict__ OutP, const float* __restrict__ bias,
    int ldA, int ldB, int ldO, int nChunks, int nLimit)
{
  __shared__ __align__(16) _Float16 As[2][128 * 64];
  __shared__ __align__(16) _Float16 Bs[2][128 * 64];

  const int t = threadIdx.x;
  const int m0 = blockIdx.x * 128;
  const int n0 = blockIdx.y * 128;
  const int wid = t >> 6;
  const int lane = t & 63;
  const int wm = (wid >> 1) * 64;
  const int wn = (wid & 1) * 64;
  const int lr = lane & 15;
  const int lg = lane >> 4;

  const int gr = lane >> 3;
  const int gcol = ((lane & 7) ^ gr) * 8;
  const _Float16* Abase = A + (size_t)(m0 + wid * 32 + gr) * ldA + gcol;
  const _Float16* Bbase = Bw + (size_t)(n0 + wid * 32 + gr) * ldB + gcol;

  f4 acc[4][4];
  #pragma unroll
  for (int i = 0; i < 4; ++i)
    #pragma unroll
    for (int j = 0; j < 4; ++j) { f4 z = {0.f, 0.f, 0.f, 0.f}; acc[i][j] = z; }

  auto issue = [&](int c, int buf) {
    #pragma unroll
    for (int i = 0; i < 4; ++i) {
      gload16(Abase + (size_t)(i * 8) * ldA + c * 64, &As[buf][(wid * 32 + i * 8) * 64]);
      gload16(Bbase + (size_t)(i * 8) * ldB + c * 64, &Bs[buf][(wid * 32 + i * 8) * 64]);
    }
  };

  auto mfma_step = [&](const _Float16* as, const _Float16* bs) {
    #pragma unroll
    for (int kk = 0; kk < 2; ++kk) {
      h8 af[4], bf[4];
      const int kslot = kk * 4 + lg;
      #pragma unroll
      for (int i = 0; i < 4; ++i) {
        const int row = wm + i * 16 + lr;
        af[i] = *reinterpret_cast<const h8*>(&as[row * 64 + ((kslot ^ (row & 7)) << 3)]);
      }
      #pragma unroll
      for (int j = 0; j < 4; ++j) {
        const int row = wn + j * 16 + lr;
        bf[j] = *reinterpret_cast<const h8*>(&bs[row * 64 + ((kslot ^ (row & 7)) << 3)]);
      }
      #pragma unroll
      for (int i = 0; i < 4; ++i)
        #pragma unroll
        for (int j = 0; j < 4; ++j)
          acc[i][j] = __builtin_amdgcn_mfma_f32_16x16x32_f16(af[i], bf[j], acc[i][j], 0, 0, 0);
    }
  };

  issue(0, 0);
  int cur = 0;
  for (int c = 0; c < nChunks; ++c) {
    __syncthreads();
    if (c + 1 < nChunks) issue(c + 1, cur ^ 1);
    mfma_step(As[cur], Bs[cur]);
    cur ^= 1;
  }

  #pragma unroll
  for (int j = 0; j < 4; ++j) {
    const int col = n0 + wn + j * 16 + lr;
    if (col >= nLimit) continue;
    float bvv = 0.0f;
    if (EPI_BIAS) bvv = bias[col];
    #pragma unroll
    for (int i = 0; i < 4; ++i) {
      const int rowb = m0 + wm + i * 16 + lg * 4;
      #pragma unroll
      for (int r = 0; r < 4; ++r) {
        float x = acc[i][j][r] + bvv;
        if (DO_ELU) x = (x > 0.0f) ? x : expm1f(x);
        if (OUT_F32)
          reinterpret_cast<float*>(OutP)[(size_t)(rowb + r) * ldO + col] = x;
        else
          reinterpret_cast<_Float16*>(OutP)[(size_t)(rowb + r) * ldO + col] = (_Float16)x;
      }
    }
  }
}

// ---------------- expert GEMM: 256x256 tile, BK=64, dbuf, 8 waves x (128x64) ----------
// virtual K tiles t = e*KCe + kc, NT = E*KCe + 1 (last = bias blend from wpad).
// All 8 stage gloads of tile t+1 issued at top of tile t; one vmcnt(0)+barrier per tile.
// LDS: A[2 buf][256][64], B[2 buf][256][64], rows 128B, slot s at phys s^(row&7)
// via pre-swizzled global source (proven 0-conflict). Gate weights transposed: wT[e][m].
template<int KCe, bool DO_ELU, bool OUT_F32>
__global__ __launch_bounds__(512, 2) void expertX_k(
    const _Float16* __restrict__ A, const _Float16* __restrict__ Bw,
    void* __restrict__ OutP, const _Float16* __restrict__ wpad,
    int ldA, int ldB, int ldO, int nLimit)
{
  constexpr int E = 10;
  constexpr int NT = E * KCe + 1;
  __shared__ __align__(16) _Float16 lds[65536 + 2560];
  _Float16* wT = lds + 65536;

  const int tid = threadIdx.x;
  const int w = tid >> 6;
  const int l = tid & 63;
  const int m0 = blockIdx.x * 256;
  const int n0 = blockIdx.y * 256;
  const int wm2 = w >> 2;        // M-half (128 rows)
  const int wn2 = w & 3;         // N-quarter (64 cols)
  const int lr = l & 15;
  const int lg = l >> 4;

  // staging: thread -> row strow, slot tid&7; source pre-swizzled
  const int strow = tid >> 3;
  const int scol = ((tid & 7) ^ (strow & 7)) * 8;

  auto stg = [&](int dstEl, const _Float16* src) {
    gload16(src, lds + dstEl + w * 512);
  };
  // stage full tile (A 4 groups + B 4 groups) into buffer `buf`
  auto issue_tile = [&](int buf, const _Float16* aSrc, size_t lda_, const _Float16* bSrc) {
    const int ab = buf * 16384;
    stg(ab,         aSrc);
    stg(ab + 4096,  aSrc + 64 * lda_);
    stg(ab + 8192,  aSrc + 128 * lda_);
    stg(ab + 12288, aSrc + 192 * lda_);
    const int bb = 32768 + buf * 16384;
    stg(bb,         bSrc);
    stg(bb + 4096,  bSrc + (size_t)64 * ldB);
    stg(bb + 8192,  bSrc + (size_t)128 * ldB);
    stg(bb + 12288, bSrc + (size_t)192 * ldB);
  };

  auto frag = [&](const _Float16* half, int rh, int kslot) -> h8 {
    return *reinterpret_cast<const h8*>(half + rh * 64 + ((kslot ^ (rh & 7)) << 3));
  };

  f4 acc[8][4];
  #pragma unroll
  for (int mi = 0; mi < 8; ++mi)
    #pragma unroll
    for (int ni = 0; ni < 4; ++ni) { f4 z = {0.f, 0.f, 0.f, 0.f}; acc[mi][ni] = z; }

  // ---- prologue: wT (transposed gate) + tile 0 ----
  for (int idx = tid; idx < 2560; idx += 512) {
    const int m = idx & 255, e = idx >> 8;
    wT[e * 256 + m] = wpad[(size_t)(m0 + m) * 64 + e];
  }
  issue_tile(0, A + (size_t)(m0 + strow) * ldA + scol, (size_t)ldA,
             Bw + (size_t)(n0 + strow) * ldB + scol);
  asm volatile("s_waitcnt vmcnt(0) lgkmcnt(0)" ::: "memory");
  __builtin_amdgcn_s_barrier();
  __builtin_amdgcn_sched_barrier(0);

  const int rb0 = (wn2 & 1) * 64 + lr;   // FIX: per-lane row term lr was missing in R6
  int t = 0;
  #pragma unroll 1
  for (int e = 0; e < E; ++e) {
    _Float16 se[8];
    #pragma unroll
    for (int j = 0; j < 8; ++j) se[j] = wT[e * 256 + wm2 * 128 + j * 16 + lr];
    #pragma unroll 1
    for (int kc = 0; kc < KCe; ++kc, ++t) {
      const _Float16* Ah = lds + (t & 1) * 16384 + wm2 * 8192;
      const _Float16* Bh = lds + 32768 + (t & 1) * 16384 + (wn2 >> 1) * 8192;

      // issue ALL stage loads for tile t+1 at tile top (max issue->wait distance)
      if (t < NT - 1) {
        const _Float16* aS; size_t la;
        if (t + 1 == NT - 1) { aS = wpad + (size_t)(m0 + strow) * 64 + scol; la = 64; }
        else {
          const int kn = (kc + 1 == KCe) ? 0 : kc + 1;
          aS = A + (size_t)(m0 + strow) * ldA + kn * 64 + scol; la = (size_t)ldA;
        }
        issue_tile((t + 1) & 1, aS, la,
                   Bw + (size_t)(n0 + strow) * ldB + (size_t)(t + 1) * 64 + scol);
      }
      __builtin_amdgcn_sched_barrier(0);

      // 4 phases: (kk, mih), 16 MFMA each; B-frags read once per kk
      #pragma unroll
      for (int kk = 0; kk < 2; ++kk) {
        h8 bf[4];
        #pragma unroll
        for (int ni = 0; ni < 4; ++ni) bf[ni] = frag(Bh, rb0 + ni * 16, kk * 4 + lg);
        #pragma unroll
        for (int mih = 0; mih < 2; ++mih) {
          h8 aa[4];
          #pragma unroll
          for (int mi = 0; mi < 4; ++mi) {
            h8 v = frag(Ah, mih * 64 + mi * 16 + lr, kk * 4 + lg);
            const _Float16 sv = se[mih * 4 + mi];
            #pragma unroll
            for (int q = 0; q < 8; ++q) v[q] = v[q] * sv;
            aa[mi] = v;
          }
          __builtin_amdgcn_s_setprio(1);
          #pragma unroll
          for (int mi = 0; mi < 4; ++mi)
            #pragma unroll
            for (int ni = 0; ni < 4; ++ni)
              acc[mih * 4 + mi][ni] =
                  __builtin_amdgcn_mfma_f32_16x16x32_f16(aa[mi], bf[ni], acc[mih * 4 + mi][ni], 0, 0, 0);
          __builtin_amdgcn_s_setprio(0);
        }
      }

      // tile boundary: tile t+1's loads were issued a full tile ago
      __builtin_amdgcn_sched_barrier(0);
      asm volatile("s_waitcnt vmcnt(0)" ::: "memory");
      __builtin_amdgcn_s_barrier();
      __builtin_amdgcn_sched_barrier(0);
    }
  }

  // ---- bias tile (t = NT-1): A = wpad rows, unscaled; resident; no staging ----
  {
    const _Float16* Ah = lds + (t & 1) * 16384 + wm2 * 8192;
    const _Float16* Bh = lds + 32768 + (t & 1) * 16384 + (wn2 >> 1) * 8192;
    #pragma unroll
    for (int kk = 0; kk < 2; ++kk) {
      h8 bf[4];
      #pragma unroll
      for (int ni = 0; ni < 4; ++ni) bf[ni] = frag(Bh, rb0 + ni * 16, kk * 4 + lg);
      #pragma unroll
      for (int mih = 0; mih < 2; ++mih) {
        h8 aa[4];
        #pragma unroll
        for (int mi = 0; mi < 4; ++mi)
          aa[mi] = frag(Ah, mih * 64 + mi * 16 + lr, kk * 4 + lg);
        #pragma unroll
        for (int mi = 0; mi < 4; ++mi)
          #pragma unroll
          for (int ni = 0; ni < 4; ++ni)
            acc[mih * 4 + mi][ni] =
                __builtin_amdgcn_mfma_f32_16x16x32_f16(aa[mi], bf[ni], acc[mih * 4 + mi][ni], 0, 0, 0);
      }
    }
  }

  // ---- epilogue ----
  #pragma unroll
  for (int ni = 0; ni < 4; ++ni) {
    const int col = n0 + wn2 * 64 + ni * 16 + lr;
    if (col >= nLimit) continue;
    #pragma unroll
    for (int mi = 0; mi < 8; ++mi) {
      const int rowb = m0 + wm2 * 128 + mi * 16 + lg * 4;
      #pragma unroll
      for (int r = 0; r < 4; ++r) {
        float x = acc[mi][ni][r];
        if (DO_ELU) x = (x > 0.0f) ? x : expm1f(x);
        if (OUT_F32)
          reinterpret_cast<float*>(OutP)[(size_t)(rowb + r) * ldO + col] = x;
        else
          reinterpret_cast<_Float16*>(OutP)[(size_t)(rowb + r) * ldO + col] = (_Float16)x;
      }
    }
  }
}

// ---------------- gating final layer (N=10) + softmax -> wpad[B][64], 4 lanes/row ----------------
__global__ __launch_bounds__(256) void gate_softmax_k(const _Float16* __restrict__ gb,
    const float* __restrict__ W2, const float* __restrict__ b2, _Float16* __restrict__ wpad)
{
  __shared__ float W2s[5120];
  for (int i = threadIdx.x; i < 5120; i += 256) W2s[i] = W2[i];
  __syncthreads();
  const int t = threadIdx.x;
  const int sub = t & 3;
  const int b = blockIdx.x * 64 + (t >> 2);
  const _Float16* row = gb + (size_t)b * 512 + sub * 128;
  float acc[10];
  #pragma unroll
  for (int o = 0; o < 10; ++o) acc[o] = 0.0f;
  #pragma unroll 4
  for (int k0 = 0; k0 < 128; k0 += 8) {
    h8 x = *reinterpret_cast<const h8*>(row + k0);
    #pragma unroll
    for (int jj = 0; jj < 8; ++jj) {
      float xv = (float)x[jj];
      const int k = sub * 128 + k0 + jj;
      #pragma unroll
      for (int o = 0; o < 10; ++o) acc[o] += xv * W2s[k * 10 + o];
    }
  }
  #pragma unroll
  for (int o = 0; o < 10; ++o) {
    acc[o] += __shfl_xor(acc[o], 1);
    acc[o] += __shfl_xor(acc[o], 2);
    acc[o] += b2[o];
  }
  float mx = acc[0];
  #pragma unroll
  for (int o = 1; o < 10; ++o) mx = fmaxf(mx, acc[o]);
  float s = 0.0f;
  #pragma unroll
  for (int o = 0; o < 10; ++o) { acc[o] = expf(acc[o] - mx); s += acc[o]; }
  const float inv = 1.0f / s;
  h8 o0 = {0,0,0,0,0,0,0,0}, o1 = {0,0,0,0,0,0,0,0};
  if (sub == 0) {
    #pragma unroll
    for (int o = 0; o < 8; ++o) o0[o] = (_Float16)(acc[o] * inv);
    o1[0] = (_Float16)(acc[8] * inv);
    o1[1] = (_Float16)(acc[9] * inv);
  }
  _Float16* wr = wpad + (size_t)b * 64 + sub * 16;
  *reinterpret_cast<h8*>(wr) = o0;
  *reinterpret_cast<h8*>(wr + 8) = o1;
}

extern "C" void kernel_launch(void* const* d_in, const int* in_sizes, int n_in,
                              void* d_out, int out_size, void* d_ws, size_t ws_size,
                              hipStream_t stream)
{
  const float* input_ = (const float*)d_in[0];
  const float* e0_W0 = (const float*)d_in[1];
  const float* e0_b0 = (const float*)d_in[2];
  const float* e0_W1 = (const float*)d_in[3];
  const float* e0_b1 = (const float*)d_in[4];
  const float* e1_W0 = (const float*)d_in[5];
  const float* e1_b0 = (const float*)d_in[6];
  const float* e1_W1 = (const float*)d_in[7];
  const float* e1_b1 = (const float*)d_in[8];
  const float* g_W0  = (const float*)d_in[9];
  const float* g_b0  = (const float*)d_in[10];
  const float* g_W1  = (const float*)d_in[11];
  const float* g_b1  = (const float*)d_in[12];
  const float* g_W2  = (const float*)d_in[13];
  const float* g_b2  = (const float*)d_in[14];
  const float* m_W0  = (const float*)d_in[15];
  const float* m_b0  = (const float*)d_in[16];
  const float* m_W1  = (const float*)d_in[17];
  const float* m_b1  = (const float*)d_in[18];
  const float* m_W2  = (const float*)d_in[19];
  const float* m_b2  = (const float*)d_in[20];
  (void)in_sizes; (void)n_in; (void)out_size; (void)ws_size;

  char* ws = (char*)d_ws;
  size_t off = 0;
  auto alloc = [&](size_t bytes) { char* p = ws + off; off += (bytes + 255) & ~(size_t)255; return p; };

  const size_t Bn = BATCH;
  _Float16* wsA    = (_Float16*)alloc(Bn * 512 * 2);  // pose16[448] -> ga16 -> x1
  _Float16* wsB    = (_Float16*)alloc(Bn * 512 * 2);  // h0a -> gb
  _Float16* wsC    = (_Float16*)alloc(Bn * 640 * 2);  // feat -> x2
  _Float16* goal16 = (_Float16*)alloc(Bn * 128 * 2);
  _Float16* gate16 = (_Float16*)alloc(Bn * 128 * 2);
  _Float16* h1a16  = (_Float16*)alloc(Bn * 128 * 2);
  _Float16* wpad16 = (_Float16*)alloc(Bn * 64 * 2);
  _Float16* e0W0t  = (_Float16*)alloc((size_t)512 * 448 * 2);
  _Float16* e0W1t  = (_Float16*)alloc((size_t)512 * 512 * 2);
  _Float16* e1W0t  = (_Float16*)alloc((size_t)128 * 128 * 2);
  _Float16* e1W1t  = (_Float16*)alloc((size_t)128 * 128 * 2);
  _Float16* gW0t   = (_Float16*)alloc((size_t)512 * 128 * 2);
  _Float16* gW1t   = (_Float16*)alloc((size_t)512 * 512 * 2);
  _Float16* W0b    = (_Float16*)alloc((size_t)512 * 6464 * 2);
  _Float16* W1b    = (_Float16*)alloc((size_t)512 * 5184 * 2);
  _Float16* W2b    = (_Float16*)alloc((size_t)768 * 5184 * 2);

  dim3 blk(256);
  const int BIG = 1 << 30;

  prep_input_k<<<BATCH, blk, 0, stream>>>(input_, wsA, goal16, gate16);

  prep_wt_k<<<dim3(7, 8),    blk, 0, stream>>>(e0_W0, e0_b0, e0W0t, 400, 512, 512, 448, 1, 0);
  prep_wt_k<<<dim3(8, 8),    blk, 0, stream>>>(e0_W1, nullptr, e0W1t, 512, 512, 512, 512, 0, 0);
  prep_wt_k<<<dim3(2, 2),    blk, 0, stream>>>(e1_W0, e1_b0, e1W0t, 78, 128, 128, 128, 1, 0);
  prep_wt_k<<<dim3(2, 2),    blk, 0, stream>>>(e1_W1, nullptr, e1W1t, 128, 128, 128, 128, 0, 0);
  prep_wt_k<<<dim3(2, 8),    blk, 0, stream>>>(g_W0, g_b0, gW0t, 78, 512, 512, 128, 1, 0);
  prep_wt_k<<<dim3(8, 8),    blk, 0, stream>>>(g_W1, nullptr, gW1t, 512, 512, 512, 512, 0, 0);
  prep_wt_k<<<dim3(101, 8),  blk, 0, stream>>>(m_W0, m_b0, W0b, 6400, 512, 512, 6464, 10, 512);
  prep_wt_k<<<dim3(81, 8),   blk, 0, stream>>>(m_W1, m_b1, W1b, 5120, 512, 512, 5184, 10, 512);
  prep_wt_k<<<dim3(81, 12),  blk, 0, stream>>>(m_W2, m_b2, W2b, 5120, 578, 578, 5184, 10, 578);

  // encoder 0: pose(448) -> h0a(512) -> feat[:,0:512]
  gemm_k<false, true, false><<<dim3(256, 4), blk, 0, stream>>>(
      wsA, e0W0t, wsB, nullptr, 448, 448, 512, 7, BIG);
  gemm_k<true, true, false><<<dim3(256, 4), blk, 0, stream>>>(
      wsB, e0W1t, wsC, e0_b1, 512, 512, 640, 8, BIG);
  // encoder 1: goal(128) -> h1a(128) -> feat[:,512:640]
  gemm_k<false, true, false><<<dim3(256, 1), blk, 0, stream>>>(
      goal16, e1W0t, h1a16, nullptr, 128, 128, 128, 2, BIG);
  gemm_k<true, true, false><<<dim3(256, 1), blk, 0, stream>>>(
      h1a16, e1W1t, wsC + 512, e1_b1, 128, 128, 640, 2, BIG);
  // gating: gate(128) -> ga(512) -> gb(512) -> softmax w
  gemm_k<false, true, false><<<dim3(256, 4), blk, 0, stream>>>(
      gate16, gW0t, wsA, nullptr, 128, 128, 512, 2, BIG);
  gemm_k<true, true, false><<<dim3(256, 4), blk, 0, stream>>>(
      wsA, gW1t, wsB, g_b1, 512, 512, 512, 8, BIG);
  gate_softmax_k<<<dim3(BATCH / 64), blk, 0, stream>>>(wsB, g_W2, g_b2, wpad16);

  // experts (256x256 dbuf): feat(640) -> x1(512) -> x2(512) -> pred(578)
  expertX_k<10, true, false><<<dim3(128, 2), dim3(512), 0, stream>>>(
      wsC, W0b, wsA, wpad16, 640, 6464, 512, BIG);
  expertX_k<8, true, false><<<dim3(128, 2), dim3(512), 0, stream>>>(
      wsA, W1b, wsC, wpad16, 512, 5184, 512, BIG);
  expertX_k<8, false, true><<<dim3(128, 3), dim3(512), 0, stream>>>(
      wsC, W2b, d_out, wpad16, 512, 5184, 578, 578);
}